// Round 1
// baseline (838.964 us; speedup 1.0000x reference)
//
#include <hip/hip_runtime.h>

// Problem constants (fixed by the reference): B=1
#define S_DIM 128
#define L_DIM 256
#define D_DIM 768
#define H_DIM 12
#define TD    2304            // 3*D
#define NROW  32768           // S*L
#define KDIM  768
#define LN_EPS 1e-5f

typedef unsigned short u16;
typedef unsigned int   u32;
typedef _Float16 f16;
typedef _Float16 f16x8 __attribute__((ext_vector_type(8)));
typedef _Float16 f16x4 __attribute__((ext_vector_type(4)));
typedef float    f32x4 __attribute__((ext_vector_type(4)));

// Workspace layout (bytes), total 224,133,120 (< 255 MB proven in rounds 1/2):
//  region R (151 MB, off 0) is time-multiplexed:
//    row phase : qt f16[H][L][8192] 50.33M | kt same | vt f16[H][8192][256] 50.33M
//    col phase : p  f16[NROW][TD]  151 MB   (GEMM2 overwrites; qt/kt/vt dead)
//  lpart  : f32 [4][H][L][L]  12,582,912   (split-K partials for row logits)
//  pt     : f16 [H][L][L]      1,572,864   (softmax probs, PV A-operand)
//  xh/u1h : f16 [NROW][D]     50,331,648
//  wr_h   : f16 [TD][D]        3,538,944
//  wc_h   : f16 [TD][D]        3,538,944
#define WS_QT_OFF     0
#define WS_KT_OFF     50331648
#define WS_VT_OFF     100663296
#define WS_P_OFF      0
#define WS_LPART_OFF  150994944
#define WS_PT_OFF     163577856
#define WS_XH_OFF     166723584
#define WS_WRH_OFF    217055232
#define WS_WCH_OFF    220594176

// fp16 staging (NOT bf16): row logits accumulate K=8192 products; bf16's
// 2^-9 rel-err gave final absmax 0.15 > 0.113 thr (round 1). fp16 passes
// at 0.047 (rounds 3-5) with fp16-input MFMA, fp32 accum.
__device__ __forceinline__ float h2f(u16 v) {
    union { u16 u; f16 h; } c; c.u = v; return (float)c.h;
}

__device__ __forceinline__ void gload_lds16(const void* g, void* l) {
    __builtin_amdgcn_global_load_lds((const __attribute__((address_space(1))) void*)g,
                                     (__attribute__((address_space(3))) void*)l, 16, 0, 0);
}

// ---------------------------------------------------------------------------
// f32 -> f16 convert, 4 elems/thread, grid sized exactly (n % 1024 == 0).
// ---------------------------------------------------------------------------
__global__ __launch_bounds__(256)
void cvt_f32_f16(const float* __restrict__ in, f16* __restrict__ out)
{
    int i = blockIdx.x * 256 + threadIdx.x;
    float4 v = ((const float4*)in)[i];
    f16x4 o; o.x = (f16)v.x; o.y = (f16)v.y; o.z = (f16)v.z; o.w = (f16)v.w;
    ((f16x4*)out)[i] = o;
}

// ---------------------------------------------------------------------------
// MFMA GEMM core (m97 pattern, used by logits/PV): 128x128 tile, BK=32,
// 256 thr = 4 waves (2x2 of 64x64), each wave 4x4 of mfma_f32_16x16x32_f16.
// global_load_lds w=16; XOR chunk swizzle j ^= (m>>1)&3 keeps frag
// ds_read_b128 2-way (free, m136).
// ---------------------------------------------------------------------------
#define MFMA_PROLOG(KROW)                                                     \
    __shared__ f16 As[128 * 32];                                              \
    __shared__ f16 Bs[128 * 32];                                              \
    const int tid  = threadIdx.x;                                             \
    const int lane = tid & 63;                                                \
    const int w    = tid >> 6;                                                \
    const int wr   = (w >> 1) * 64;                                           \
    const int wc   = (w & 1) * 64;                                            \
    const int lm   = lane & 15;                                               \
    const int q    = lane >> 4;                                               \
    size_t soff[2];                                                           \
    int    ldsc[2];                                                           \
    _Pragma("unroll")                                                         \
    for (int t = 0; t < 2; ++t) {                                             \
        int c  = w * 128 + t * 64 + lane;                                     \
        int m  = c >> 2;                                                      \
        int gj = (c & 3) ^ ((m >> 1) & 3);                                    \
        soff[t] = (size_t)m * (KROW) + gj * 8;                                \
        ldsc[t] = (w * 128 + t * 64) * 8;                                     \
    }                                                                         \
    int chA[4], chB[4];                                                       \
    _Pragma("unroll")                                                         \
    for (int t = 0; t < 4; ++t) {                                             \
        int ma = wr + t * 16 + lm;                                            \
        chA[t] = ma * 4 + (q ^ ((ma >> 1) & 3));                              \
        int mb = wc + t * 16 + lm;                                            \
        chB[t] = mb * 4 + (q ^ ((mb >> 1) & 3));                              \
    }                                                                         \
    f32x4 acc[4][4];                                                          \
    _Pragma("unroll")                                                         \
    for (int i = 0; i < 4; ++i)                                               \
        _Pragma("unroll")                                                     \
        for (int j = 0; j < 4; ++j) acc[i][j] = (f32x4)0.f;

#define MFMA_KLOOP(baseA, baseB, KLEN)                                        \
    for (int k0 = 0; k0 < (KLEN); k0 += 32) {                                 \
        _Pragma("unroll")                                                     \
        for (int t = 0; t < 2; ++t) {                                         \
            gload_lds16((baseA) + soff[t] + k0, &As[ldsc[t]]);                \
            gload_lds16((baseB) + soff[t] + k0, &Bs[ldsc[t]]);                \
        }                                                                     \
        __syncthreads();                                                      \
        f16x8 af[4], bf[4];                                                   \
        _Pragma("unroll")                                                     \
        for (int t = 0; t < 4; ++t) af[t] = *(const f16x8*)&As[chA[t] * 8];   \
        _Pragma("unroll")                                                     \
        for (int t = 0; t < 4; ++t) bf[t] = *(const f16x8*)&Bs[chB[t] * 8];   \
        _Pragma("unroll")                                                     \
        for (int mt = 0; mt < 4; ++mt)                                        \
            _Pragma("unroll")                                                 \
            for (int nt = 0; nt < 4; ++nt)                                    \
                acc[mt][nt] = __builtin_amdgcn_mfma_f32_16x16x32_f16(         \
                    af[mt], bf[nt], acc[mt][nt], 0, 0, 0);                    \
        __syncthreads();                                                      \
    }

// ---------------------------------------------------------------------------
// 256x256-tile GEMM core: BK=64, 512 thr = 8 waves (2M x 4N), wave tile
// 128x64 = 8x4 fragments. Double-buffered LDS (4 x 32 KB = 128 KB),
// 2-phase pipeline (T3 minimal recipe): stage(t+1) issued BEFORE compute(t),
// ONE vmcnt(0)+barrier per 64-wide K-tile (vs 2 per 32-wide step in m97).
// Static buffer names + unroll-by-2 let alias analysis keep the in-flight
// global_load_lds from forcing vmcnt(0) before the ds_reads.
// Swizzle: row of 8 16B-chunks, chunk j stored at j ^ (row&7); source
// pre-swizzled (global addr permuted), LDS linear, read applies same XOR.
// 64 lanes -> 8 lanes per 16B chunk position -> uniform banks (conflict-free).
// ---------------------------------------------------------------------------
#define G256_PROLOG(KROW)                                                     \
    __shared__ f16 As0[256 * 64];                                             \
    __shared__ f16 Bs0[256 * 64];                                             \
    __shared__ f16 As1[256 * 64];                                             \
    __shared__ f16 Bs1[256 * 64];                                             \
    const int tid  = threadIdx.x;                                             \
    const int lane = tid & 63;                                                \
    const int w    = tid >> 6;                                                \
    const int wr   = (w >> 2) * 128;                                          \
    const int wc   = (w & 3) * 64;                                            \
    const int lm   = lane & 15;                                               \
    const int q    = lane >> 4;                                               \
    size_t soff[4];                                                           \
    int    ldsb[4];                                                           \
    _Pragma("unroll")                                                         \
    for (int i = 0; i < 4; ++i) {                                             \
        int c = i * 512 + tid;                                                \
        int r = c >> 3;                                                       \
        int j = (c & 7) ^ (r & 7);                                            \
        soff[i] = (size_t)r * (KROW) + j * 8;                                 \
        ldsb[i] = (i * 512 + w * 64) * 8;                                     \
    }                                                                         \
    f32x4 acc[8][4];                                                          \
    _Pragma("unroll")                                                         \
    for (int i = 0; i < 8; ++i)                                               \
        _Pragma("unroll")                                                     \
        for (int j = 0; j < 4; ++j) acc[i][j] = (f32x4)0.f;

#define G256_STAGE(Ad, Bd, baseA, baseB, kk)                                  \
    _Pragma("unroll")                                                         \
    for (int i = 0; i < 4; ++i) {                                             \
        gload_lds16((baseA) + soff[i] + (kk) * 64, &Ad[ldsb[i]]);             \
        gload_lds16((baseB) + soff[i] + (kk) * 64, &Bd[ldsb[i]]);             \
    }

#define G256_FRAG(buf, row, ks)                                               \
    (*(const f16x8*)&buf[(size_t)(row) * 64 +                                 \
                         ((((ks) * 4 + q) ^ ((row) & 7)) * 8)])

#define G256_COMPUTE(Ab, Bb)                                                  \
    _Pragma("unroll")                                                         \
    for (int ks = 0; ks < 2; ++ks) {                                          \
        f16x8 af[8], bf[4];                                                   \
        _Pragma("unroll")                                                     \
        for (int mt = 0; mt < 8; ++mt)                                        \
            af[mt] = G256_FRAG(Ab, wr + mt * 16 + lm, ks);                    \
        _Pragma("unroll")                                                     \
        for (int nt = 0; nt < 4; ++nt)                                        \
            bf[nt] = G256_FRAG(Bb, wc + nt * 16 + lm, ks);                    \
        __builtin_amdgcn_s_setprio(1);                                        \
        _Pragma("unroll")                                                     \
        for (int mt = 0; mt < 8; ++mt)                                        \
            _Pragma("unroll")                                                 \
            for (int nt = 0; nt < 4; ++nt)                                    \
                acc[mt][nt] = __builtin_amdgcn_mfma_f32_16x16x32_f16(         \
                    af[mt], bf[nt], acc[mt][nt], 0, 0, 0);                    \
        __builtin_amdgcn_s_setprio(0);                                        \
    }

// KLEN/64 must be even (768/64 = 12).
#define G256_KLOOP(baseA, baseB, KLEN)                                        \
    G256_STAGE(As0, Bs0, baseA, baseB, 0)                                     \
    __syncthreads();                                                          \
    _Pragma("clang loop unroll(disable)")                                     \
    for (int kk = 0; kk < (KLEN) / 64; kk += 2) {                             \
        G256_STAGE(As1, Bs1, baseA, baseB, kk + 1)                            \
        G256_COMPUTE(As0, Bs0)                                                \
        __syncthreads();                                                      \
        if (kk + 2 < (KLEN) / 64) {                                           \
            G256_STAGE(As0, Bs0, baseA, baseB, kk + 2)                        \
        }                                                                     \
        G256_COMPUTE(As1, Bs1)                                                \
        __syncthreads();                                                      \
    }

// XCD-aware bijective swizzle: nwg = 9*128 = 1152 = 8 * 144 (divisible).
// Blocks resident on one XCD cover a compact 16-row-panel x all-9-col group
// -> A panels stay L2/L3-local.
#define G256_SWIZZLE()                                                        \
    const int wg   = blockIdx.y * 9 + blockIdx.x;                             \
    const int swz  = (wg & 7) * 144 + (wg >> 3);                              \
    const int row0 = (swz / 9) * 256;                                         \
    const int col0 = (swz % 9) * 256;

// ---------------------------------------------------------------------------
// GEMM2 (col QKV): C = A*W^T + bias -> p f16 [NROW][TD]. grid (9, 128) x512.
// ---------------------------------------------------------------------------
__global__ __launch_bounds__(512, 2)
void mfma_gemm_qkv(const f16* __restrict__ A, const f16* __restrict__ W,
                   const float* __restrict__ bias, f16* __restrict__ C)
{
    G256_SWIZZLE()
    G256_PROLOG(KDIM)
    const f16* baseA = A + (size_t)row0 * KDIM;
    const f16* baseB = W + (size_t)col0 * KDIM;
    G256_KLOOP(baseA, baseB, KDIM)

    // C/D layout: col=lane&15, row=quad*4+reg
    float bv[4];
#pragma unroll
    for (int nt = 0; nt < 4; ++nt) bv[nt] = bias[col0 + wc + nt * 16 + lm];
#pragma unroll
    for (int mt = 0; mt < 8; ++mt) {
        int grow = row0 + wr + mt * 16 + q * 4;
#pragma unroll
        for (int nt = 0; nt < 4; ++nt) {
            int gcol = col0 + wc + nt * 16 + lm;
#pragma unroll
            for (int r = 0; r < 4; ++r)
                C[(size_t)(grow + r) * TD + gcol] = (f16)(acc[mt][nt][r] + bv[nt]);
        }
    }
}

// ---------------------------------------------------------------------------
// GEMM1 (row QKV): same core but scatter epilogue:
//   q -> qt[h][i][s*64+c]       (K-major for the logits GEMM)
//   k -> kt[h][j][s*64+c]
//   v -> vt[h][s*64+d][j]       (K=j-major for the PV GEMM; r-consecutive
//                                accumulator elems = consecutive j -> f16x4)
// col0 tiles (256-wide) never straddle the 768/1536 q/k/v boundaries.
// ---------------------------------------------------------------------------
__global__ __launch_bounds__(512, 2)
void mfma_gemm_row(const f16* __restrict__ A, const f16* __restrict__ W,
                   const float* __restrict__ bias,
                   f16* __restrict__ qt, f16* __restrict__ kt,
                   f16* __restrict__ vt)
{
    G256_SWIZZLE()
    G256_PROLOG(KDIM)
    const f16* baseA = A + (size_t)row0 * KDIM;
    const f16* baseB = W + (size_t)col0 * KDIM;
    G256_KLOOP(baseA, baseB, KDIM)

    if (col0 < 1536) {
        f16* dst = (col0 < 768) ? qt : kt;
        const int cbase = (col0 < 768) ? col0 : col0 - 768;
#pragma unroll
        for (int nt = 0; nt < 4; ++nt) {
            int gcol = cbase + wc + nt * 16 + lm;
            int h = gcol >> 6, c = gcol & 63;
            float b = bias[col0 + wc + nt * 16 + lm];
#pragma unroll
            for (int mt = 0; mt < 8; ++mt) {
                int n0 = row0 + wr + mt * 16 + q * 4;
#pragma unroll
                for (int r = 0; r < 4; ++r) {
                    int n = n0 + r;
                    int s = n >> 8, ii = n & 255;
                    dst[(((size_t)h * 256 + ii) * 128 + s) * 64 + c] =
                        (f16)(acc[mt][nt][r] + b);
                }
            }
        }
    } else {
#pragma unroll
        for (int nt = 0; nt < 4; ++nt) {
            int gcol = col0 + wc + nt * 16 + lm;
            int vcol = gcol - 1536;
            int h = vcol >> 6, d = vcol & 63;
            float b = bias[gcol];
#pragma unroll
            for (int mt = 0; mt < 8; ++mt) {
                int n0 = row0 + wr + mt * 16 + q * 4;
                int s = n0 >> 8, j0 = n0 & 255;   // r stays within one s
                f16x4 pack;
#pragma unroll
                for (int r = 0; r < 4; ++r) pack[r] = (f16)(acc[mt][nt][r] + b);
                *(f16x4*)&vt[((((size_t)h * 128 + s) * 64 + d) << 8) + j0] = pack;
            }
        }
    }
}

// ---------------------------------------------------------------------------
// Row logits via MFMA: split-K=4 partials. grid (2, 2, 48): z = h*4+sp.
// ---------------------------------------------------------------------------
__global__ __launch_bounds__(256)
void row_logits_mfma(const f16* __restrict__ qt, const f16* __restrict__ kt,
                     float* __restrict__ lpart)
{
    const int i0 = blockIdx.y * 128;
    const int j0 = blockIdx.x * 128;
    const int h  = blockIdx.z >> 2;
    const int sp = blockIdx.z & 3;
    MFMA_PROLOG(8192)
    const f16* baseA = qt + ((size_t)h * 256 + i0) * 8192 + sp * 2048;
    const f16* baseB = kt + ((size_t)h * 256 + j0) * 8192 + sp * 2048;
    MFMA_KLOOP(baseA, baseB, 2048)

    float* outp = lpart + (size_t)(sp * 12 + h) * 65536;
#pragma unroll
    for (int mt = 0; mt < 4; ++mt) {
        int grow = i0 + wr + mt * 16 + q * 4;
#pragma unroll
        for (int nt = 0; nt < 4; ++nt) {
            int gcol = j0 + wc + nt * 16 + lm;
#pragma unroll
            for (int r = 0; r < 4; ++r)
                outp[(size_t)(grow + r) * 256 + gcol] = acc[mt][nt][r];
        }
    }
}

// ---------------------------------------------------------------------------
// softmax over rows of 256, summing 4 split-K partials; probs out f16.
// grid = H*L, block 256.
// ---------------------------------------------------------------------------
__global__ __launch_bounds__(256)
void softmax256_4(const float* __restrict__ lpart, f16* __restrict__ pt)
{
    __shared__ float red[256];
    const int t = threadIdx.x;
    const size_t idx = (size_t)blockIdx.x * 256 + t;
    const size_t P = (size_t)12 * 65536;
    float v = lpart[idx] + lpart[idx + P] + lpart[idx + 2*P] + lpart[idx + 3*P];
    red[t] = v; __syncthreads();
    for (int w = 128; w > 0; w >>= 1) { if (t < w) red[t] = fmaxf(red[t], red[t+w]); __syncthreads(); }
    float m = red[0];
    __syncthreads();
    float e = __expf(v - m);
    red[t] = e; __syncthreads();
    for (int w = 128; w > 0; w >>= 1) { if (t < w) red[t] += red[t+w]; __syncthreads(); }
    pt[idx] = (f16)(e / red[0]);
}

// ---------------------------------------------------------------------------
// Row PV via MFMA: per h, out[i,(s,d)] = sum_j pt[h][i][j] * vt[h][(s,d)][j].
// M=256(i), N=8192(s*64+d), K=256(j). grid (64 ntiles, 2 mtiles, 12 h).
// Epilogue: rout[(s*256+i)*768 + h*64 + d], f32, 16-lane contiguous in d.
// ---------------------------------------------------------------------------
__global__ __launch_bounds__(256)
void row_pv_mfma(const f16* __restrict__ pt, const f16* __restrict__ vt,
                 float* __restrict__ rout)
{
    const int n0t = blockIdx.x * 128;
    const int i0  = blockIdx.y * 128;
    const int h   = blockIdx.z;
    MFMA_PROLOG(256)
    const f16* baseA = pt + (size_t)h * 65536 + (size_t)i0 * 256;
    const f16* baseB = vt + ((size_t)h * 8192 + n0t) * 256;
    MFMA_KLOOP(baseA, baseB, 256)

#pragma unroll
    for (int mt = 0; mt < 4; ++mt) {
        int irow = i0 + wr + mt * 16 + q * 4;
#pragma unroll
        for (int nt = 0; nt < 4; ++nt) {
            int n = n0t + wc + nt * 16 + lm;
            int s = n >> 6, d = n & 63;
#pragma unroll
            for (int r = 0; r < 4; ++r)
                rout[(size_t)(s * 256 + irow + r) * D_DIM + h * 64 + d] =
                    acc[mt][nt][r];
        }
    }
}

// ---------------------------------------------------------------------------
// out1_h = f16(LN(x + r)); x,r f32. grid NROW, block 256.
// ---------------------------------------------------------------------------
__global__ __launch_bounds__(256)
void add_ln_out16(const float* __restrict__ x, const float* __restrict__ r,
                  const float* __restrict__ g, const float* __restrict__ beta,
                  f16* __restrict__ out16)
{
    __shared__ float red[256];
    const int n = blockIdx.x, t = threadIdx.x;
    const float* xp = x + (size_t)n * D_DIM;
    const float* rp = r + (size_t)n * D_DIM;
    float v[3]; float s = 0.f;
#pragma unroll
    for (int e = 0; e < 3; ++e) { v[e] = xp[t + e*256] + rp[t + e*256]; s += v[e]; }
    red[t] = s; __syncthreads();
    for (int w = 128; w > 0; w >>= 1) { if (t < w) red[t] += red[t+w]; __syncthreads(); }
    float mean = red[0] * (1.f/768.f);
    __syncthreads();
    float sq = 0.f;
#pragma unroll
    for (int e = 0; e < 3; ++e) { float d = v[e] - mean; sq += d*d; }
    red[t] = sq; __syncthreads();
    for (int w = 128; w > 0; w >>= 1) { if (t < w) red[t] += red[t+w]; __syncthreads(); }
    float rstd = rsqrtf(red[0] * (1.f/768.f) + LN_EPS);
#pragma unroll
    for (int e = 0; e < 3; ++e) {
        int idx = t + e*256;
        out16[(size_t)n * D_DIM + idx] = (f16)((v[e] - mean) * rstd * g[idx] + beta[idx]);
    }
}

// ---------------------------------------------------------------------------
// out = LN(x16 + r) f32, in place on r. grid NROW, block 256.
// ---------------------------------------------------------------------------
__global__ __launch_bounds__(256)
void add_ln_in16(const f16* __restrict__ x16, float* __restrict__ r,
                 const float* __restrict__ g, const float* __restrict__ beta)
{
    __shared__ float red[256];
    const int n = blockIdx.x, t = threadIdx.x;
    const f16*   xp = x16 + (size_t)n * D_DIM;
    float*       rp = r   + (size_t)n * D_DIM;
    float v[3]; float s = 0.f;
#pragma unroll
    for (int e = 0; e < 3; ++e) { v[e] = (float)xp[t + e*256] + rp[t + e*256]; s += v[e]; }
    red[t] = s; __syncthreads();
    for (int w = 128; w > 0; w >>= 1) { if (t < w) red[t] += red[t+w]; __syncthreads(); }
    float mean = red[0] * (1.f/768.f);
    __syncthreads();
    float sq = 0.f;
#pragma unroll
    for (int e = 0; e < 3; ++e) { float d = v[e] - mean; sq += d*d; }
    red[t] = sq; __syncthreads();
    for (int w = 128; w > 0; w >>= 1) { if (t < w) red[t] += red[t+w]; __syncthreads(); }
    float rstd = rsqrtf(red[0] * (1.f/768.f) + LN_EPS);
#pragma unroll
    for (int e = 0; e < 3; ++e) {
        int idx = t + e*256;
        rp[idx] = (v[e] - mean) * rstd * g[idx] + beta[idx];
    }
}

// ---------------------------------------------------------------------------
// Column attention via MFMA. One block per (l,h): grid (256, 12), 256 thr =
// 4 waves; wave w owns i-rows [w*32, w*32+32). Softmax in-register on the
// C-layout (quad shuffles), 1/sum deferred to the PV epilogue.
// LDS: Qs/Ks [128][72]; Ps [128][136] overlays; Vt [64][136]. 54,272 B.
// ---------------------------------------------------------------------------
__global__ __launch_bounds__(256, 3)
void col_attn_mfma(const f16* __restrict__ p, float* __restrict__ cout)
{
    __shared__ char smem[54272];
    f16* Qs = (f16*)smem;             // [128][72]
    f16* Ks = (f16*)(smem + 18432);   // [128][72]
    f16* Ps = (f16*)smem;             // [128][136] overlay (after barrier)
    f16* Vt = (f16*)(smem + 36864);   // [64][136]

    const int tid  = threadIdx.x;
    const int lane = tid & 63;
    const int w    = tid >> 6;
    const int lm   = lane & 15;
    const int q    = lane >> 4;
    const int l = blockIdx.x, h = blockIdx.y;
    const int ib = w * 32;

    // ---- phase 1: stage Q,K row-major; V transposed into Vt[d][j]
    {
        const int r  = tid >> 1;          // s index 0..127
        const int hc = (tid & 1) * 32;    // c half
        const f16* rowp = p + (size_t)(r * 256 + l) * TD + h * 64 + hc;
#pragma unroll
        for (int cc = 0; cc < 4; ++cc)
            *(float4*)&Qs[r * 72 + hc + cc * 8] = *(const float4*)(rowp + cc * 8);
#pragma unroll
        for (int cc = 0; cc < 4; ++cc)
            *(float4*)&Ks[r * 72 + hc + cc * 8] = *(const float4*)(rowp + 768 + cc * 8);
#pragma unroll
        for (int cc = 0; cc < 4; ++cc) {
            union { float4 f; u16 u[8]; } vb;
            vb.f = *(const float4*)(rowp + 1536 + cc * 8);
#pragma unroll
            for (int e = 0; e < 8; ++e) {
                int d = hc + cc * 8 + e;
                ((u16*)Vt)[d * 136 + r] = vb.u[e];
            }
        }
    }
    __syncthreads();

    // ---- phase 2: S = Q K^T (wave tile 32x128: 2 mt x 8 nt x 2 ksteps)
    f32x4 acc[2][8];
#pragma unroll
    for (int mt = 0; mt < 2; ++mt)
#pragma unroll
        for (int nt = 0; nt < 8; ++nt) acc[mt][nt] = (f32x4)0.f;
#pragma unroll
    for (int ks = 0; ks < 2; ++ks) {
        f16x8 af[2];
#pragma unroll
        for (int mt = 0; mt < 2; ++mt)
            af[mt] = *(const f16x8*)&Qs[(ib + mt * 16 + lm) * 72 + ks * 32 + q * 8];
#pragma unroll
        for (int nt = 0; nt < 8; ++nt) {
            f16x8 bf = *(const f16x8*)&Ks[(nt * 16 + lm) * 72 + ks * 32 + q * 8];
#pragma unroll
            for (int mt = 0; mt < 2; ++mt)
                acc[mt][nt] = __builtin_amdgcn_mfma_f32_16x16x32_f16(
                    af[mt], bf, acc[mt][nt], 0, 0, 0);
        }
    }
    __syncthreads();   // all Qs/Ks frag reads done before Ps overlay writes

    // ---- phase 3: softmax over j in C-layout; write exp to Ps (f16)
    float inv_sum[2][4];
#pragma unroll
    for (int mt = 0; mt < 2; ++mt) {
#pragma unroll
        for (int r = 0; r < 4; ++r) {
            float m = acc[mt][0][r];
#pragma unroll
            for (int nt = 1; nt < 8; ++nt) m = fmaxf(m, acc[mt][nt][r]);
#pragma unroll
            for (int d = 1; d < 16; d <<= 1) m = fmaxf(m, __shfl_xor(m, d));
            float s = 0.f;
#pragma unroll
            for (int nt = 0; nt < 8; ++nt) {
                float e = __expf(acc[mt][nt][r] - m);
                acc[mt][nt][r] = e; s += e;
            }
#pragma unroll
            for (int d = 1; d < 16; d <<= 1) s += __shfl_xor(s, d);
            inv_sum[mt][r] = 1.f / s;
        }
        const int irow = ib + mt * 16 + q * 4;
#pragma unroll
        for (int nt = 0; nt < 8; ++nt) {
            const int jj = nt * 16 + lm;
#pragma unroll
            for (int r = 0; r < 4; ++r)
                Ps[(irow + r) * 136 + jj] = (f16)acc[mt][nt][r];
        }
    }
    __syncthreads();

    // ---- phase 4: O = P~ V (wave tile 32x64: 2 mt x 4 nt x 4 ksteps)
    f32x4 acc2[2][4];
#pragma unroll
    for (int mt = 0; mt < 2; ++mt)
#pragma unroll
        for (int nt = 0; nt < 4; ++nt) acc2[mt][nt] = (f32x4)0.f;
#pragma unroll
    for (int ks = 0; ks < 4; ++ks) {
        f16x8 pf[2];
#pragma unroll
        for (int mt = 0; mt < 2; ++mt)
            pf[mt] = *(const f16x8*)&Ps[(ib + mt * 16 + lm) * 136 + ks * 32 + q * 8];
#pragma unroll
        for (int nt = 0; nt < 4; ++nt) {
            f16x8 vf = *(const f16x8*)&Vt[(nt * 16 + lm) * 136 + ks * 32 + q * 8];
#pragma unroll
            for (int mt = 0; mt < 2; ++mt)
                acc2[mt][nt] = __builtin_amdgcn_mfma_f32_16x16x32_f16(
                    pf[mt], vf, acc2[mt][nt], 0, 0, 0);
        }
    }

    // ---- epilogue: apply deferred 1/sum, write f32
#pragma unroll
    for (int mt = 0; mt < 2; ++mt) {
        const int irow = ib + mt * 16 + q * 4;
#pragma unroll
        for (int nt = 0; nt < 4; ++nt) {
            const int d = nt * 16 + lm;
#pragma unroll
            for (int r = 0; r < 4; ++r)
                cout[(size_t)((irow + r) * 256 + l) * D_DIM + h * 64 + d] =
                    acc2[mt][nt][r] * inv_sum[mt][r];
        }
    }
}

// ---------------------------------------------------------------------------
extern "C" void kernel_launch(void* const* d_in, const int* in_sizes, int n_in,
                              void* d_out, int out_size, void* d_ws, size_t ws_size,
                              hipStream_t stream)
{
    const float* x     = (const float*)d_in[0];
    const float* w_row = (const float*)d_in[1];
    const float* b_row = (const float*)d_in[2];
    const float* w_col = (const float*)d_in[3];
    const float* b_col = (const float*)d_in[4];
    const float* g1    = (const float*)d_in[5];
    const float* be1   = (const float*)d_in[6];
    const float* g2    = (const float*)d_in[7];
    const float* be2   = (const float*)d_in[8];
    float* out = (float*)d_out;

    char* ws = (char*)d_ws;
    f16*   qt     = (f16*)(ws + WS_QT_OFF);
    f16*   kt     = (f16*)(ws + WS_KT_OFF);
    f16*   vt     = (f16*)(ws + WS_VT_OFF);
    f16*   p      = (f16*)(ws + WS_P_OFF);      // col phase, aliases qt/kt/vt
    float* lpart  = (float*)(ws + WS_LPART_OFF);
    f16*   pt     = (f16*)(ws + WS_PT_OFF);
    f16*   xh     = (f16*)(ws + WS_XH_OFF);     // also out1_h after step 5
    f16*   wrh    = (f16*)(ws + WS_WRH_OFF);
    f16*   wch    = (f16*)(ws + WS_WCH_OFF);

    // 0) f32 -> f16 converts
    cvt_f32_f16<<<NROW * D_DIM / 1024, 256, 0, stream>>>(x, xh);
    cvt_f32_f16<<<TD * D_DIM / 1024, 256, 0, stream>>>(w_row, wrh);
    cvt_f32_f16<<<TD * D_DIM / 1024, 256, 0, stream>>>(w_col, wch);
    // 1) row QKV projection (256^2 2-phase MFMA) -> qt/kt (K-major) + vt (j-major)
    mfma_gemm_row<<<dim3(9, 128), 512, 0, stream>>>(xh, wrh, b_row, qt, kt, vt);
    // 2) tied row logits (MFMA, split-K=4)
    row_logits_mfma<<<dim3(2, 2, 48), 256, 0, stream>>>(qt, kt, lpart);
    // 3) softmax over j (sums 4 partials) -> f16 probs
    softmax256_4<<<H_DIM * L_DIM, 256, 0, stream>>>(lpart, pt);
    // 4) row PV (MFMA) -> d_out (scratch)
    row_pv_mfma<<<dim3(64, 2, H_DIM), 256, 0, stream>>>(pt, vt, out);
    // 5) out1_h = f16(LN(x + row_out))  (xh dead; reuse as out1_h)
    add_ln_out16<<<NROW, 256, 0, stream>>>(x, out, g1, be1, xh);
    // 6) col QKV projection (256^2 2-phase MFMA) -> p (overwrites qt/kt/vt region)
    mfma_gemm_qkv<<<dim3(9, 128), 512, 0, stream>>>(xh, wch, b_col, p);
    // 7) column attention (MFMA) -> d_out (scratch)
    col_attn_mfma<<<dim3(L_DIM, H_DIM), 256, 0, stream>>>(p, out);
    // 8) out = LN(out1_h + col_out), in place on d_out
    add_ln_in16<<<NROW, 256, 0, stream>>>(xh, out, g2, be2);
}

// Round 2
// 734.141 us; speedup vs baseline: 1.1428x; 1.1428x over previous
//
#include <hip/hip_runtime.h>

// Problem constants (fixed by the reference): B=1
#define S_DIM 128
#define L_DIM 256
#define D_DIM 768
#define H_DIM 12
#define TD    2304            // 3*D
#define NROW  32768           // S*L
#define KDIM  768
#define LN_EPS 1e-5f

typedef unsigned short u16;
typedef unsigned int   u32;
typedef _Float16 f16;
typedef _Float16 f16x8 __attribute__((ext_vector_type(8)));
typedef _Float16 f16x4 __attribute__((ext_vector_type(4)));
typedef float    f32x4 __attribute__((ext_vector_type(4)));

// Workspace layout (bytes), total 224,133,120 (< 255 MB proven in rounds 1/2):
//  region R (151 MB, off 0) is time-multiplexed:
//    row phase : qt f16[H][L][8192] 50.33M | kt same | vt f16[H][8192][256] 50.33M
//    col phase : p  f16[NROW][TD]  151 MB   (GEMM2 overwrites; qt/kt/vt dead)
//  lpart  : f32 [4][H][L][L]  12,582,912   (split-K partials for row logits)
//  pt     : f16 [H][L][L]      1,572,864   (softmax probs, PV A-operand)
//  xh/u1h : f16 [NROW][D]     50,331,648
//  wr_h   : f16 [TD][D]        3,538,944
//  wc_h   : f16 [TD][D]        3,538,944
#define WS_QT_OFF     0
#define WS_KT_OFF     50331648
#define WS_VT_OFF     100663296
#define WS_P_OFF      0
#define WS_LPART_OFF  150994944
#define WS_PT_OFF     163577856
#define WS_XH_OFF     166723584
#define WS_WRH_OFF    217055232
#define WS_WCH_OFF    220594176

// fp16 staging (NOT bf16): row logits accumulate K=8192 products; bf16's
// 2^-9 rel-err gave final absmax 0.15 > 0.113 thr (round 1). fp16 passes
// at 0.047 (rounds 3-5) with fp16-input MFMA, fp32 accum.
__device__ __forceinline__ float h2f(u16 v) {
    union { u16 u; f16 h; } c; c.u = v; return (float)c.h;
}

__device__ __forceinline__ void gload_lds16(const void* g, void* l) {
    __builtin_amdgcn_global_load_lds((const __attribute__((address_space(1))) void*)g,
                                     (__attribute__((address_space(3))) void*)l, 16, 0, 0);
}

// ---------------------------------------------------------------------------
// f32 -> f16 convert, 4 elems/thread, grid sized exactly (n % 1024 == 0).
// ---------------------------------------------------------------------------
__global__ __launch_bounds__(256)
void cvt_f32_f16(const float* __restrict__ in, f16* __restrict__ out)
{
    int i = blockIdx.x * 256 + threadIdx.x;
    float4 v = ((const float4*)in)[i];
    f16x4 o; o.x = (f16)v.x; o.y = (f16)v.y; o.z = (f16)v.z; o.w = (f16)v.w;
    ((f16x4*)out)[i] = o;
}

// ---------------------------------------------------------------------------
// MFMA GEMM core (m97 pattern, used by logits/PV): 128x128 tile, BK=32,
// 256 thr = 4 waves (2x2 of 64x64), each wave 4x4 of mfma_f32_16x16x32_f16.
// global_load_lds w=16; XOR chunk swizzle j ^= (m>>1)&3 keeps frag
// ds_read_b128 2-way (free, m136).
// ---------------------------------------------------------------------------
#define MFMA_PROLOG(KROW)                                                     \
    __shared__ f16 As[128 * 32];                                              \
    __shared__ f16 Bs[128 * 32];                                              \
    const int tid  = threadIdx.x;                                             \
    const int lane = tid & 63;                                                \
    const int w    = tid >> 6;                                                \
    const int wr   = (w >> 1) * 64;                                           \
    const int wc   = (w & 1) * 64;                                            \
    const int lm   = lane & 15;                                               \
    const int q    = lane >> 4;                                               \
    size_t soff[2];                                                           \
    int    ldsc[2];                                                           \
    _Pragma("unroll")                                                         \
    for (int t = 0; t < 2; ++t) {                                             \
        int c  = w * 128 + t * 64 + lane;                                     \
        int m  = c >> 2;                                                      \
        int gj = (c & 3) ^ ((m >> 1) & 3);                                    \
        soff[t] = (size_t)m * (KROW) + gj * 8;                                \
        ldsc[t] = (w * 128 + t * 64) * 8;                                     \
    }                                                                         \
    int chA[4], chB[4];                                                       \
    _Pragma("unroll")                                                         \
    for (int t = 0; t < 4; ++t) {                                             \
        int ma = wr + t * 16 + lm;                                            \
        chA[t] = ma * 4 + (q ^ ((ma >> 1) & 3));                              \
        int mb = wc + t * 16 + lm;                                            \
        chB[t] = mb * 4 + (q ^ ((mb >> 1) & 3));                              \
    }                                                                         \
    f32x4 acc[4][4];                                                          \
    _Pragma("unroll")                                                         \
    for (int i = 0; i < 4; ++i)                                               \
        _Pragma("unroll")                                                     \
        for (int j = 0; j < 4; ++j) acc[i][j] = (f32x4)0.f;

#define MFMA_KLOOP(baseA, baseB, KLEN)                                        \
    for (int k0 = 0; k0 < (KLEN); k0 += 32) {                                 \
        _Pragma("unroll")                                                     \
        for (int t = 0; t < 2; ++t) {                                         \
            gload_lds16((baseA) + soff[t] + k0, &As[ldsc[t]]);                \
            gload_lds16((baseB) + soff[t] + k0, &Bs[ldsc[t]]);                \
        }                                                                     \
        __syncthreads();                                                      \
        f16x8 af[4], bf[4];                                                   \
        _Pragma("unroll")                                                     \
        for (int t = 0; t < 4; ++t) af[t] = *(const f16x8*)&As[chA[t] * 8];   \
        _Pragma("unroll")                                                     \
        for (int t = 0; t < 4; ++t) bf[t] = *(const f16x8*)&Bs[chB[t] * 8];   \
        _Pragma("unroll")                                                     \
        for (int mt = 0; mt < 4; ++mt)                                        \
            _Pragma("unroll")                                                 \
            for (int nt = 0; nt < 4; ++nt)                                    \
                acc[mt][nt] = __builtin_amdgcn_mfma_f32_16x16x32_f16(         \
                    af[mt], bf[nt], acc[mt][nt], 0, 0, 0);                    \
        __syncthreads();                                                      \
    }

// ---------------------------------------------------------------------------
// 256x256-tile GEMM core, 8-phase-style schedule (T3+T4, plain HIP):
// BK=64, 512 thr = 8 waves (2M x 4N), wave tile 128x64 = 8x4 fragments.
// Double-buffered LDS (4 x 32 KB = 128 KB). Per K-tile: 4 phases of
// {ds_read frag subtile | issue 4 global_load_lds for tile t+1 | setprio(1)
//  16 MFMA setprio(0)}; NO __syncthreads in the loop (it force-drains
// vmcnt(0)+lgkmcnt(0) -- the round-1 regression). One asm vmcnt(0) + raw
// s_barrier + sched_barrier(0) per K-tile boundary; prefetch issued in
// phases 0-1 has ~3 phases of MFMA cover by then.
// Swizzle: row of 8 16B-chunks, chunk j stored at j ^ (row&7); source
// pre-swizzled, LDS linear, read applies same XOR (proven round 1,
// SQ_LDS_BANK_CONFLICT = 0).
// ---------------------------------------------------------------------------
#define G256_PROLOG(KROW)                                                     \
    __shared__ f16 As0[256 * 64];                                             \
    __shared__ f16 Bs0[256 * 64];                                             \
    __shared__ f16 As1[256 * 64];                                             \
    __shared__ f16 Bs1[256 * 64];                                             \
    const int tid  = threadIdx.x;                                             \
    const int lane = tid & 63;                                                \
    const int w    = tid >> 6;                                                \
    const int wr   = (w >> 2) * 128;                                          \
    const int wc   = (w & 3) * 64;                                            \
    const int lm   = lane & 15;                                               \
    const int q    = lane >> 4;                                               \
    size_t soff[4];                                                           \
    int    ldsb[4];                                                           \
    _Pragma("unroll")                                                         \
    for (int i = 0; i < 4; ++i) {                                             \
        int c = i * 512 + tid;                                                \
        int r = c >> 3;                                                       \
        int j = (c & 7) ^ (r & 7);                                            \
        soff[i] = (size_t)r * (KROW) + j * 8;                                 \
        ldsb[i] = (i * 512 + w * 64) * 8;                                     \
    }                                                                         \
    f32x4 acc[8][4];                                                          \
    _Pragma("unroll")                                                         \
    for (int i = 0; i < 8; ++i)                                               \
        _Pragma("unroll")                                                     \
        for (int j = 0; j < 4; ++j) acc[i][j] = (f32x4)0.f;

#define G256_STAGE(Ad, Bd, baseA, baseB, kk)                                  \
    _Pragma("unroll")                                                         \
    for (int i = 0; i < 4; ++i) {                                             \
        gload_lds16((baseA) + soff[i] + (size_t)(kk) * 64, &Ad[ldsb[i]]);     \
        gload_lds16((baseB) + soff[i] + (size_t)(kk) * 64, &Bd[ldsb[i]]);     \
    }

#define G256_FRAG(buf, row, ks)                                               \
    (*(const f16x8*)&buf[(size_t)(row) * 64 +                                 \
                         ((((ks) * 4 + q) ^ ((row) & 7)) * 8)])

// One K-tile (BK=64): compute from (Ac,Bc), prefetch tile kknext into (An,Bn)
// if PF. 4 phases; boundary = asm vmcnt(0) + raw s_barrier + sched fence.
#define G256_TILE(Ac, Bc, An, Bn, kknext, PF)                                 \
  {                                                                           \
    f16x8 af[8], bf[4];                                                       \
    /* phase 0: A frags + B frags nt0-1 @ks0; prefetch next A */              \
    _Pragma("unroll")                                                         \
    for (int mt = 0; mt < 8; ++mt) af[mt] = G256_FRAG(Ac, wr + mt*16 + lm, 0);\
    _Pragma("unroll")                                                         \
    for (int nt = 0; nt < 2; ++nt) bf[nt] = G256_FRAG(Bc, wc + nt*16 + lm, 0);\
    if (PF) {                                                                 \
      _Pragma("unroll")                                                       \
      for (int i = 0; i < 4; ++i)                                             \
        gload_lds16(baseA + soff[i] + (size_t)(kknext) * 64, &An[ldsb[i]]);   \
    }                                                                         \
    __builtin_amdgcn_s_setprio(1);                                            \
    _Pragma("unroll")                                                         \
    for (int mt = 0; mt < 8; ++mt)                                            \
      _Pragma("unroll")                                                       \
      for (int nt = 0; nt < 2; ++nt)                                          \
        acc[mt][nt] = __builtin_amdgcn_mfma_f32_16x16x32_f16(                 \
            af[mt], bf[nt], acc[mt][nt], 0, 0, 0);                            \
    __builtin_amdgcn_s_setprio(0);                                            \
    __builtin_amdgcn_sched_barrier(0);                                        \
    /* phase 1: B frags nt2-3 @ks0; prefetch next B */                        \
    _Pragma("unroll")                                                         \
    for (int nt = 2; nt < 4; ++nt) bf[nt] = G256_FRAG(Bc, wc + nt*16 + lm, 0);\
    if (PF) {                                                                 \
      _Pragma("unroll")                                                       \
      for (int i = 0; i < 4; ++i)                                             \
        gload_lds16(baseB + soff[i] + (size_t)(kknext) * 64, &Bn[ldsb[i]]);   \
    }                                                                         \
    __builtin_amdgcn_s_setprio(1);                                            \
    _Pragma("unroll")                                                         \
    for (int mt = 0; mt < 8; ++mt)                                            \
      _Pragma("unroll")                                                       \
      for (int nt = 2; nt < 4; ++nt)                                          \
        acc[mt][nt] = __builtin_amdgcn_mfma_f32_16x16x32_f16(                 \
            af[mt], bf[nt], acc[mt][nt], 0, 0, 0);                            \
    __builtin_amdgcn_s_setprio(0);                                            \
    __builtin_amdgcn_sched_barrier(0);                                        \
    /* phase 2: A frags + B frags nt0-1 @ks1 */                               \
    _Pragma("unroll")                                                         \
    for (int mt = 0; mt < 8; ++mt) af[mt] = G256_FRAG(Ac, wr + mt*16 + lm, 1);\
    _Pragma("unroll")                                                         \
    for (int nt = 0; nt < 2; ++nt) bf[nt] = G256_FRAG(Bc, wc + nt*16 + lm, 1);\
    __builtin_amdgcn_s_setprio(1);                                            \
    _Pragma("unroll")                                                         \
    for (int mt = 0; mt < 8; ++mt)                                            \
      _Pragma("unroll")                                                       \
      for (int nt = 0; nt < 2; ++nt)                                          \
        acc[mt][nt] = __builtin_amdgcn_mfma_f32_16x16x32_f16(                 \
            af[mt], bf[nt], acc[mt][nt], 0, 0, 0);                            \
    __builtin_amdgcn_s_setprio(0);                                            \
    __builtin_amdgcn_sched_barrier(0);                                        \
    /* phase 3: B frags nt2-3 @ks1 */                                         \
    _Pragma("unroll")                                                         \
    for (int nt = 2; nt < 4; ++nt) bf[nt] = G256_FRAG(Bc, wc + nt*16 + lm, 1);\
    __builtin_amdgcn_s_setprio(1);                                            \
    _Pragma("unroll")                                                         \
    for (int mt = 0; mt < 8; ++mt)                                            \
      _Pragma("unroll")                                                       \
      for (int nt = 2; nt < 4; ++nt)                                          \
        acc[mt][nt] = __builtin_amdgcn_mfma_f32_16x16x32_f16(                 \
            af[mt], bf[nt], acc[mt][nt], 0, 0, 0);                            \
    __builtin_amdgcn_s_setprio(0);                                            \
    /* K-tile boundary: the ONLY wait+barrier (prefetch had 3 phases cover) */\
    asm volatile("s_waitcnt vmcnt(0)" ::: "memory");                          \
    __builtin_amdgcn_s_barrier();                                             \
    __builtin_amdgcn_sched_barrier(0);                                        \
  }

// KDIM = 768 -> 12 K-tiles; main loop unrolled by 2, last 2 tiles peeled.
#define G256_KLOOP768(baseA, baseB)                                           \
    G256_STAGE(As0, Bs0, baseA, baseB, 0)                                     \
    asm volatile("s_waitcnt vmcnt(0)" ::: "memory");                          \
    __builtin_amdgcn_s_barrier();                                             \
    __builtin_amdgcn_sched_barrier(0);                                        \
    _Pragma("clang loop unroll(disable)")                                     \
    for (int kk = 0; kk < 10; kk += 2) {                                      \
        G256_TILE(As0, Bs0, As1, Bs1, kk + 1, 1)                              \
        G256_TILE(As1, Bs1, As0, Bs0, kk + 2, 1)                              \
    }                                                                         \
    G256_TILE(As0, Bs0, As1, Bs1, 11, 1)                                      \
    G256_TILE(As1, Bs1, As0, Bs0, 0, 0)

// XCD-aware bijective swizzle: nwg = 9*128 = 1152 = 8 * 144 (divisible).
#define G256_SWIZZLE()                                                        \
    const int wg   = blockIdx.y * 9 + blockIdx.x;                             \
    const int swz  = (wg & 7) * 144 + (wg >> 3);                              \
    const int row0 = (swz / 9) * 256;                                         \
    const int col0 = (swz % 9) * 256;

// ---------------------------------------------------------------------------
// GEMM2 (col QKV): C = A*W^T + bias -> p f16 [NROW][TD]. grid (9, 128) x512.
// ---------------------------------------------------------------------------
__global__ __launch_bounds__(512, 2)
void mfma_gemm_qkv(const f16* __restrict__ A, const f16* __restrict__ W,
                   const float* __restrict__ bias, f16* __restrict__ C)
{
    G256_SWIZZLE()
    G256_PROLOG(KDIM)
    const f16* baseA = A + (size_t)row0 * KDIM;
    const f16* baseB = W + (size_t)col0 * KDIM;
    G256_KLOOP768(baseA, baseB)

    // C/D layout: col=lane&15, row=quad*4+reg
    float bv[4];
#pragma unroll
    for (int nt = 0; nt < 4; ++nt) bv[nt] = bias[col0 + wc + nt * 16 + lm];
#pragma unroll
    for (int mt = 0; mt < 8; ++mt) {
        int grow = row0 + wr + mt * 16 + q * 4;
#pragma unroll
        for (int nt = 0; nt < 4; ++nt) {
            int gcol = col0 + wc + nt * 16 + lm;
#pragma unroll
            for (int r = 0; r < 4; ++r)
                C[(size_t)(grow + r) * TD + gcol] = (f16)(acc[mt][nt][r] + bv[nt]);
        }
    }
}

// ---------------------------------------------------------------------------
// GEMM1 (row QKV): same core but scatter epilogue:
//   q -> qt[h][i][s*64+c]       (K-major for the logits GEMM)
//   k -> kt[h][j][s*64+c]
//   v -> vt[h][s*64+d][j]       (K=j-major for the PV GEMM; r-consecutive
//                                accumulator elems = consecutive j -> f16x4)
// col0 tiles (256-wide) never straddle the 768/1536 q/k/v boundaries.
// ---------------------------------------------------------------------------
__global__ __launch_bounds__(512, 2)
void mfma_gemm_row(const f16* __restrict__ A, const f16* __restrict__ W,
                   const float* __restrict__ bias,
                   f16* __restrict__ qt, f16* __restrict__ kt,
                   f16* __restrict__ vt)
{
    G256_SWIZZLE()
    G256_PROLOG(KDIM)
    const f16* baseA = A + (size_t)row0 * KDIM;
    const f16* baseB = W + (size_t)col0 * KDIM;
    G256_KLOOP768(baseA, baseB)

    if (col0 < 1536) {
        f16* dst = (col0 < 768) ? qt : kt;
        const int cbase = (col0 < 768) ? col0 : col0 - 768;
#pragma unroll
        for (int nt = 0; nt < 4; ++nt) {
            int gcol = cbase + wc + nt * 16 + lm;
            int h = gcol >> 6, c = gcol & 63;
            float b = bias[col0 + wc + nt * 16 + lm];
#pragma unroll
            for (int mt = 0; mt < 8; ++mt) {
                int n0 = row0 + wr + mt * 16 + q * 4;
#pragma unroll
                for (int r = 0; r < 4; ++r) {
                    int n = n0 + r;
                    int s = n >> 8, ii = n & 255;
                    dst[(((size_t)h * 256 + ii) * 128 + s) * 64 + c] =
                        (f16)(acc[mt][nt][r] + b);
                }
            }
        }
    } else {
#pragma unroll
        for (int nt = 0; nt < 4; ++nt) {
            int gcol = col0 + wc + nt * 16 + lm;
            int vcol = gcol - 1536;
            int h = vcol >> 6, d = vcol & 63;
            float b = bias[gcol];
#pragma unroll
            for (int mt = 0; mt < 8; ++mt) {
                int n0 = row0 + wr + mt * 16 + q * 4;
                int s = n0 >> 8, j0 = n0 & 255;   // r stays within one s
                f16x4 pack;
#pragma unroll
                for (int r = 0; r < 4; ++r) pack[r] = (f16)(acc[mt][nt][r] + b);
                *(f16x4*)&vt[((((size_t)h * 128 + s) * 64 + d) << 8) + j0] = pack;
            }
        }
    }
}

// ---------------------------------------------------------------------------
// Row logits via MFMA: split-K=4 partials. grid (2, 2, 48): z = h*4+sp.
// ---------------------------------------------------------------------------
__global__ __launch_bounds__(256)
void row_logits_mfma(const f16* __restrict__ qt, const f16* __restrict__ kt,
                     float* __restrict__ lpart)
{
    const int i0 = blockIdx.y * 128;
    const int j0 = blockIdx.x * 128;
    const int h  = blockIdx.z >> 2;
    const int sp = blockIdx.z & 3;
    MFMA_PROLOG(8192)
    const f16* baseA = qt + ((size_t)h * 256 + i0) * 8192 + sp * 2048;
    const f16* baseB = kt + ((size_t)h * 256 + j0) * 8192 + sp * 2048;
    MFMA_KLOOP(baseA, baseB, 2048)

    float* outp = lpart + (size_t)(sp * 12 + h) * 65536;
#pragma unroll
    for (int mt = 0; mt < 4; ++mt) {
        int grow = i0 + wr + mt * 16 + q * 4;
#pragma unroll
        for (int nt = 0; nt < 4; ++nt) {
            int gcol = j0 + wc + nt * 16 + lm;
#pragma unroll
            for (int r = 0; r < 4; ++r)
                outp[(size_t)(grow + r) * 256 + gcol] = acc[mt][nt][r];
        }
    }
}

// ---------------------------------------------------------------------------
// softmax over rows of 256, summing 4 split-K partials; probs out f16.
// grid = H*L, block 256.
// ---------------------------------------------------------------------------
__global__ __launch_bounds__(256)
void softmax256_4(const float* __restrict__ lpart, f16* __restrict__ pt)
{
    __shared__ float red[256];
    const int t = threadIdx.x;
    const size_t idx = (size_t)blockIdx.x * 256 + t;
    const size_t P = (size_t)12 * 65536;
    float v = lpart[idx] + lpart[idx + P] + lpart[idx + 2*P] + lpart[idx + 3*P];
    red[t] = v; __syncthreads();
    for (int w = 128; w > 0; w >>= 1) { if (t < w) red[t] = fmaxf(red[t], red[t+w]); __syncthreads(); }
    float m = red[0];
    __syncthreads();
    float e = __expf(v - m);
    red[t] = e; __syncthreads();
    for (int w = 128; w > 0; w >>= 1) { if (t < w) red[t] += red[t+w]; __syncthreads(); }
    pt[idx] = (f16)(e / red[0]);
}

// ---------------------------------------------------------------------------
// Row PV via MFMA: per h, out[i,(s,d)] = sum_j pt[h][i][j] * vt[h][(s,d)][j].
// M=256(i), N=8192(s*64+d), K=256(j). grid (64 ntiles, 2 mtiles, 12 h).
// Epilogue: rout[(s*256+i)*768 + h*64 + d], f32, 16-lane contiguous in d.
// ---------------------------------------------------------------------------
__global__ __launch_bounds__(256)
void row_pv_mfma(const f16* __restrict__ pt, const f16* __restrict__ vt,
                 float* __restrict__ rout)
{
    const int n0t = blockIdx.x * 128;
    const int i0  = blockIdx.y * 128;
    const int h   = blockIdx.z;
    MFMA_PROLOG(256)
    const f16* baseA = pt + (size_t)h * 65536 + (size_t)i0 * 256;
    const f16* baseB = vt + ((size_t)h * 8192 + n0t) * 256;
    MFMA_KLOOP(baseA, baseB, 256)

#pragma unroll
    for (int mt = 0; mt < 4; ++mt) {
        int irow = i0 + wr + mt * 16 + q * 4;
#pragma unroll
        for (int nt = 0; nt < 4; ++nt) {
            int n = n0t + wc + nt * 16 + lm;
            int s = n >> 6, d = n & 63;
#pragma unroll
            for (int r = 0; r < 4; ++r)
                rout[(size_t)(s * 256 + irow + r) * D_DIM + h * 64 + d] =
                    acc[mt][nt][r];
        }
    }
}

// ---------------------------------------------------------------------------
// out1_h = f16(LN(x + r)); x,r f32. grid NROW, block 256.
// ---------------------------------------------------------------------------
__global__ __launch_bounds__(256)
void add_ln_out16(const float* __restrict__ x, const float* __restrict__ r,
                  const float* __restrict__ g, const float* __restrict__ beta,
                  f16* __restrict__ out16)
{
    __shared__ float red[256];
    const int n = blockIdx.x, t = threadIdx.x;
    const float* xp = x + (size_t)n * D_DIM;
    const float* rp = r + (size_t)n * D_DIM;
    float v[3]; float s = 0.f;
#pragma unroll
    for (int e = 0; e < 3; ++e) { v[e] = xp[t + e*256] + rp[t + e*256]; s += v[e]; }
    red[t] = s; __syncthreads();
    for (int w = 128; w > 0; w >>= 1) { if (t < w) red[t] += red[t+w]; __syncthreads(); }
    float mean = red[0] * (1.f/768.f);
    __syncthreads();
    float sq = 0.f;
#pragma unroll
    for (int e = 0; e < 3; ++e) { float d = v[e] - mean; sq += d*d; }
    red[t] = sq; __syncthreads();
    for (int w = 128; w > 0; w >>= 1) { if (t < w) red[t] += red[t+w]; __syncthreads(); }
    float rstd = rsqrtf(red[0] * (1.f/768.f) + LN_EPS);
#pragma unroll
    for (int e = 0; e < 3; ++e) {
        int idx = t + e*256;
        out16[(size_t)n * D_DIM + idx] = (f16)((v[e] - mean) * rstd * g[idx] + beta[idx]);
    }
}

// ---------------------------------------------------------------------------
// out = LN(x16 + r) f32, in place on r. grid NROW, block 256.
// ---------------------------------------------------------------------------
__global__ __launch_bounds__(256)
void add_ln_in16(const f16* __restrict__ x16, float* __restrict__ r,
                 const float* __restrict__ g, const float* __restrict__ beta)
{
    __shared__ float red[256];
    const int n = blockIdx.x, t = threadIdx.x;
    const f16*   xp = x16 + (size_t)n * D_DIM;
    float*       rp = r   + (size_t)n * D_DIM;
    float v[3]; float s = 0.f;
#pragma unroll
    for (int e = 0; e < 3; ++e) { v[e] = (float)xp[t + e*256] + rp[t + e*256]; s += v[e]; }
    red[t] = s; __syncthreads();
    for (int w = 128; w > 0; w >>= 1) { if (t < w) red[t] += red[t+w]; __syncthreads(); }
    float mean = red[0] * (1.f/768.f);
    __syncthreads();
    float sq = 0.f;
#pragma unroll
    for (int e = 0; e < 3; ++e) { float d = v[e] - mean; sq += d*d; }
    red[t] = sq; __syncthreads();
    for (int w = 128; w > 0; w >>= 1) { if (t < w) red[t] += red[t+w]; __syncthreads(); }
    float rstd = rsqrtf(red[0] * (1.f/768.f) + LN_EPS);
#pragma unroll
    for (int e = 0; e < 3; ++e) {
        int idx = t + e*256;
        rp[idx] = (v[e] - mean) * rstd * g[idx] + beta[idx];
    }
}

// ---------------------------------------------------------------------------
// Column attention via MFMA. One block per (l,h): grid (256, 12), 256 thr =
// 4 waves; wave w owns i-rows [w*32, w*32+32). Softmax in-register on the
// C-layout (quad shuffles), 1/sum deferred to the PV epilogue.
// LDS: Qs/Ks [128][72]; Ps [128][136] overlays; Vt [64][136]. 54,272 B.
// ---------------------------------------------------------------------------
__global__ __launch_bounds__(256, 3)
void col_attn_mfma(const f16* __restrict__ p, float* __restrict__ cout)
{
    __shared__ char smem[54272];
    f16* Qs = (f16*)smem;             // [128][72]
    f16* Ks = (f16*)(smem + 18432);   // [128][72]
    f16* Ps = (f16*)smem;             // [128][136] overlay (after barrier)
    f16* Vt = (f16*)(smem + 36864);   // [64][136]

    const int tid  = threadIdx.x;
    const int lane = tid & 63;
    const int w    = tid >> 6;
    const int lm   = lane & 15;
    const int q    = lane >> 4;
    const int l = blockIdx.x, h = blockIdx.y;
    const int ib = w * 32;

    // ---- phase 1: stage Q,K row-major; V transposed into Vt[d][j]
    {
        const int r  = tid >> 1;          // s index 0..127
        const int hc = (tid & 1) * 32;    // c half
        const f16* rowp = p + (size_t)(r * 256 + l) * TD + h * 64 + hc;
#pragma unroll
        for (int cc = 0; cc < 4; ++cc)
            *(float4*)&Qs[r * 72 + hc + cc * 8] = *(const float4*)(rowp + cc * 8);
#pragma unroll
        for (int cc = 0; cc < 4; ++cc)
            *(float4*)&Ks[r * 72 + hc + cc * 8] = *(const float4*)(rowp + 768 + cc * 8);
#pragma unroll
        for (int cc = 0; cc < 4; ++cc) {
            union { float4 f; u16 u[8]; } vb;
            vb.f = *(const float4*)(rowp + 1536 + cc * 8);
#pragma unroll
            for (int e = 0; e < 8; ++e) {
                int d = hc + cc * 8 + e;
                ((u16*)Vt)[d * 136 + r] = vb.u[e];
            }
        }
    }
    __syncthreads();

    // ---- phase 2: S = Q K^T (wave tile 32x128: 2 mt x 8 nt x 2 ksteps)
    f32x4 acc[2][8];
#pragma unroll
    for (int mt = 0; mt < 2; ++mt)
#pragma unroll
        for (int nt = 0; nt < 8; ++nt) acc[mt][nt] = (f32x4)0.f;
#pragma unroll
    for (int ks = 0; ks < 2; ++ks) {
        f16x8 af[2];
#pragma unroll
        for (int mt = 0; mt < 2; ++mt)
            af[mt] = *(const f16x8*)&Qs[(ib + mt * 16 + lm) * 72 + ks * 32 + q * 8];
#pragma unroll
        for (int nt = 0; nt < 8; ++nt) {
            f16x8 bf = *(const f16x8*)&Ks[(nt * 16 + lm) * 72 + ks * 32 + q * 8];
#pragma unroll
            for (int mt = 0; mt < 2; ++mt)
                acc[mt][nt] = __builtin_amdgcn_mfma_f32_16x16x32_f16(
                    af[mt], bf, acc[mt][nt], 0, 0, 0);
        }
    }
    __syncthreads();   // all Qs/Ks frag reads done before Ps overlay writes

    // ---- phase 3: softmax over j in C-layout; write exp to Ps (f16)
    float inv_sum[2][4];
#pragma unroll
    for (int mt = 0; mt < 2; ++mt) {
#pragma unroll
        for (int r = 0; r < 4; ++r) {
            float m = acc[mt][0][r];
#pragma unroll
            for (int nt = 1; nt < 8; ++nt) m = fmaxf(m, acc[mt][nt][r]);
#pragma unroll
            for (int d = 1; d < 16; d <<= 1) m = fmaxf(m, __shfl_xor(m, d));
            float s = 0.f;
#pragma unroll
            for (int nt = 0; nt < 8; ++nt) {
                float e = __expf(acc[mt][nt][r] - m);
                acc[mt][nt][r] = e; s += e;
            }
#pragma unroll
            for (int d = 1; d < 16; d <<= 1) s += __shfl_xor(s, d);
            inv_sum[mt][r] = 1.f / s;
        }
        const int irow = ib + mt * 16 + q * 4;
#pragma unroll
        for (int nt = 0; nt < 8; ++nt) {
            const int jj = nt * 16 + lm;
#pragma unroll
            for (int r = 0; r < 4; ++r)
                Ps[(irow + r) * 136 + jj] = (f16)acc[mt][nt][r];
        }
    }
    __syncthreads();

    // ---- phase 4: O = P~ V (wave tile 32x64: 2 mt x 4 nt x 4 ksteps)
    f32x4 acc2[2][4];
#pragma unroll
    for (int mt = 0; mt < 2; ++mt)
#pragma unroll
        for (int nt = 0; nt < 4; ++nt) acc2[mt][nt] = (f32x4)0.f;
#pragma unroll
    for (int ks = 0; ks < 4; ++ks) {
        f16x8 pf[2];
#pragma unroll
        for (int mt = 0; mt < 2; ++mt)
            pf[mt] = *(const f16x8*)&Ps[(ib + mt * 16 + lm) * 136 + ks * 32 + q * 8];
#pragma unroll
        for (int nt = 0; nt < 4; ++nt) {
            f16x8 vf = *(const f16x8*)&Vt[(nt * 16 + lm) * 136 + ks * 32 + q * 8];
#pragma unroll
            for (int mt = 0; mt < 2; ++mt)
                acc2[mt][nt] = __builtin_amdgcn_mfma_f32_16x16x32_f16(
                    pf[mt], vf, acc2[mt][nt], 0, 0, 0);
        }
    }

    // ---- epilogue: apply deferred 1/sum, write f32
#pragma unroll
    for (int mt = 0; mt < 2; ++mt) {
        const int irow = ib + mt * 16 + q * 4;
#pragma unroll
        for (int nt = 0; nt < 4; ++nt) {
            const int d = nt * 16 + lm;
#pragma unroll
            for (int r = 0; r < 4; ++r)
                cout[(size_t)((irow + r) * 256 + l) * D_DIM + h * 64 + d] =
                    acc2[mt][nt][r] * inv_sum[mt][r];
        }
    }
}

// ---------------------------------------------------------------------------
extern "C" void kernel_launch(void* const* d_in, const int* in_sizes, int n_in,
                              void* d_out, int out_size, void* d_ws, size_t ws_size,
                              hipStream_t stream)
{
    const float* x     = (const float*)d_in[0];
    const float* w_row = (const float*)d_in[1];
    const float* b_row = (const float*)d_in[2];
    const float* w_col = (const float*)d_in[3];
    const float* b_col = (const float*)d_in[4];
    const float* g1    = (const float*)d_in[5];
    const float* be1   = (const float*)d_in[6];
    const float* g2    = (const float*)d_in[7];
    const float* be2   = (const float*)d_in[8];
    float* out = (float*)d_out;

    char* ws = (char*)d_ws;
    f16*   qt     = (f16*)(ws + WS_QT_OFF);
    f16*   kt     = (f16*)(ws + WS_KT_OFF);
    f16*   vt     = (f16*)(ws + WS_VT_OFF);
    f16*   p      = (f16*)(ws + WS_P_OFF);      // col phase, aliases qt/kt/vt
    float* lpart  = (float*)(ws + WS_LPART_OFF);
    f16*   pt     = (f16*)(ws + WS_PT_OFF);
    f16*   xh     = (f16*)(ws + WS_XH_OFF);     // also out1_h after step 5
    f16*   wrh    = (f16*)(ws + WS_WRH_OFF);
    f16*   wch    = (f16*)(ws + WS_WCH_OFF);

    // 0) f32 -> f16 converts
    cvt_f32_f16<<<NROW * D_DIM / 1024, 256, 0, stream>>>(x, xh);
    cvt_f32_f16<<<TD * D_DIM / 1024, 256, 0, stream>>>(w_row, wrh);
    cvt_f32_f16<<<TD * D_DIM / 1024, 256, 0, stream>>>(w_col, wch);
    // 1) row QKV projection (256^2 8-phase MFMA) -> qt/kt (K-major) + vt (j-major)
    mfma_gemm_row<<<dim3(9, 128), 512, 0, stream>>>(xh, wrh, b_row, qt, kt, vt);
    // 2) tied row logits (MFMA, split-K=4)
    row_logits_mfma<<<dim3(2, 2, 48), 256, 0, stream>>>(qt, kt, lpart);
    // 3) softmax over j (sums 4 partials) -> f16 probs
    softmax256_4<<<H_DIM * L_DIM, 256, 0, stream>>>(lpart, pt);
    // 4) row PV (MFMA) -> d_out (scratch)
    row_pv_mfma<<<dim3(64, 2, H_DIM), 256, 0, stream>>>(pt, vt, out);
    // 5) out1_h = f16(LN(x + row_out))  (xh dead; reuse as out1_h)
    add_ln_out16<<<NROW, 256, 0, stream>>>(x, out, g1, be1, xh);
    // 6) col QKV projection (256^2 8-phase MFMA) -> p (overwrites qt/kt/vt region)
    mfma_gemm_qkv<<<dim3(9, 128), 512, 0, stream>>>(xh, wch, b_col, p);
    // 7) column attention (MFMA) -> d_out (scratch)
    col_attn_mfma<<<dim3(L_DIM, H_DIM), 256, 0, stream>>>(p, out);
    // 8) out = LN(out1_h + col_out), in place on d_out
    add_ln_in16<<<NROW, 256, 0, stream>>>(xh, out, g2, be2);
}

// Round 3
// 725.221 us; speedup vs baseline: 1.1568x; 1.0123x over previous
//
#include <hip/hip_runtime.h>

// Problem constants (fixed by the reference): B=1
#define S_DIM 128
#define L_DIM 256
#define D_DIM 768
#define H_DIM 12
#define TD    2304            // 3*D
#define NROW  32768           // S*L
#define KDIM  768
#define LN_EPS 1e-5f

typedef unsigned short u16;
typedef unsigned int   u32;
typedef _Float16 f16;
typedef _Float16 f16x8 __attribute__((ext_vector_type(8)));
typedef _Float16 f16x4 __attribute__((ext_vector_type(4)));
typedef float    f32x4 __attribute__((ext_vector_type(4)));

// Workspace layout (bytes), total 224,133,120:
//  region R (151 MB, off 0) is time-multiplexed:
//    row phase : qt f16[H][L][8192] 50.33M | kt same | vt f16[H][8192][256] 50.33M
//    col phase : p  f16[NROW][TD]  151 MB   (GEMM2 overwrites; qt/kt/vt dead)
#define WS_QT_OFF     0
#define WS_KT_OFF     50331648
#define WS_VT_OFF     100663296
#define WS_P_OFF      0
#define WS_LPART_OFF  150994944
#define WS_PT_OFF     163577856
#define WS_XH_OFF     166723584
#define WS_WRH_OFF    217055232
#define WS_WCH_OFF    220594176

// fp16 staging (NOT bf16): row logits accumulate K=8192 products; bf16 failed
// absmax. fp16 passes at 0.047 with fp16-input MFMA, fp32 accum.
__device__ __forceinline__ void gload_lds16(const void* g, void* l) {
    __builtin_amdgcn_global_load_lds((const __attribute__((address_space(1))) void*)g,
                                     (__attribute__((address_space(3))) void*)l, 16, 0, 0);
}

// ---------------------------------------------------------------------------
// f32 -> f16 convert, 4 elems/thread, grid sized exactly (n % 1024 == 0).
// ---------------------------------------------------------------------------
__global__ __launch_bounds__(256)
void cvt_f32_f16(const float* __restrict__ in, f16* __restrict__ out)
{
    int i = blockIdx.x * 256 + threadIdx.x;
    float4 v = ((const float4*)in)[i];
    f16x4 o; o.x = (f16)v.x; o.y = (f16)v.y; o.z = (f16)v.z; o.w = (f16)v.w;
    ((f16x4*)out)[i] = o;
}

// ---------------------------------------------------------------------------
// MFMA GEMM core (m97 pattern, used by logits/PV): 128x128 tile, BK=32,
// 256 thr = 4 waves (2x2 of 64x64), each wave 4x4 of mfma_f32_16x16x32_f16.
// ---------------------------------------------------------------------------
#define MFMA_PROLOG(KROW)                                                     \
    __shared__ f16 As[128 * 32];                                              \
    __shared__ f16 Bs[128 * 32];                                              \
    const int tid  = threadIdx.x;                                             \
    const int lane = tid & 63;                                                \
    const int w    = tid >> 6;                                                \
    const int wr   = (w >> 1) * 64;                                           \
    const int wc   = (w & 1) * 64;                                            \
    const int lm   = lane & 15;                                               \
    const int q    = lane >> 4;                                               \
    size_t soff[2];                                                           \
    int    ldsc[2];                                                           \
    _Pragma("unroll")                                                         \
    for (int t = 0; t < 2; ++t) {                                             \
        int c  = w * 128 + t * 64 + lane;                                     \
        int m  = c >> 2;                                                      \
        int gj = (c & 3) ^ ((m >> 1) & 3);                                    \
        soff[t] = (size_t)m * (KROW) + gj * 8;                                \
        ldsc[t] = (w * 128 + t * 64) * 8;                                     \
    }                                                                         \
    int chA[4], chB[4];                                                       \
    _Pragma("unroll")                                                         \
    for (int t = 0; t < 4; ++t) {                                             \
        int ma = wr + t * 16 + lm;                                            \
        chA[t] = ma * 4 + (q ^ ((ma >> 1) & 3));                              \
        int mb = wc + t * 16 + lm;                                            \
        chB[t] = mb * 4 + (q ^ ((mb >> 1) & 3));                              \
    }                                                                         \
    f32x4 acc[4][4];                                                          \
    _Pragma("unroll")                                                         \
    for (int i = 0; i < 4; ++i)                                               \
        _Pragma("unroll")                                                     \
        for (int j = 0; j < 4; ++j) acc[i][j] = (f32x4)0.f;

#define MFMA_KLOOP(baseA, baseB, KLEN)                                        \
    for (int k0 = 0; k0 < (KLEN); k0 += 32) {                                 \
        _Pragma("unroll")                                                     \
        for (int t = 0; t < 2; ++t) {                                         \
            gload_lds16((baseA) + soff[t] + k0, &As[ldsc[t]]);                \
            gload_lds16((baseB) + soff[t] + k0, &Bs[ldsc[t]]);                \
        }                                                                     \
        __syncthreads();                                                      \
        f16x8 af[4], bf[4];                                                   \
        _Pragma("unroll")                                                     \
        for (int t = 0; t < 4; ++t) af[t] = *(const f16x8*)&As[chA[t] * 8];   \
        _Pragma("unroll")                                                     \
        for (int t = 0; t < 4; ++t) bf[t] = *(const f16x8*)&Bs[chB[t] * 8];   \
        _Pragma("unroll")                                                     \
        for (int mt = 0; mt < 4; ++mt)                                        \
            _Pragma("unroll")                                                 \
            for (int nt = 0; nt < 4; ++nt)                                    \
                acc[mt][nt] = __builtin_amdgcn_mfma_f32_16x16x32_f16(         \
                    af[mt], bf[nt], acc[mt][nt], 0, 0, 0);                    \
        __syncthreads();                                                      \
    }

// ---------------------------------------------------------------------------
// 256x192-tile GEMM core with counted-vmcnt ring (T3+T4):
// BK=64, 512 thr = 8 waves (4M x 2N), wave tile 64x96 = 4x6 fragments.
// LDS: A ring-3 (3 x 32 KB) + B ring-2 (2 x 24 KB) = 144 KB.
// Per tile t: s_waitcnt vmcnt(4) [forces A(t),B(t) landed; leaves A(t+1)'s
// 4 loads in flight -- NEVER drains to 0 in the loop], one raw s_barrier +
// sched_barrier(0); then issue stage B(t+1) (3 loads) and A(t+2) (4 loads);
// then ds_read frags + 48 MFMA. Staging thus overlaps 1-2 tiles of compute.
// Race-safety: every wave waits vmcnt BEFORE the barrier, so post-barrier all
// waves' tile-t loads have landed; stage targets were last read before the
// PREVIOUS barrier (ds_reads retire before MFMA which precedes the barrier).
// Swizzle: row of 8 16B-chunks, chunk j stored at j ^ (row&7); source
// pre-swizzled, LDS linear, read applies same XOR (proven: 0 bank conflicts).
// ---------------------------------------------------------------------------
#define R3_WAIT_(N) asm volatile("s_waitcnt vmcnt(" #N ")" ::: "memory")
#define R3_WAIT(N)  R3_WAIT_(N)

#define R3_PROLOG()                                                           \
    __shared__ f16 As0[256 * 64];                                             \
    __shared__ f16 As1[256 * 64];                                             \
    __shared__ f16 As2[256 * 64];                                             \
    __shared__ f16 Bs0[192 * 64];                                             \
    __shared__ f16 Bs1[192 * 64];                                             \
    const int tid  = threadIdx.x;                                             \
    const int lane = tid & 63;                                                \
    const int w    = tid >> 6;                                                \
    const int wr   = (w >> 1) * 64;                                           \
    const int wc   = (w & 1) * 96;                                            \
    const int lm   = lane & 15;                                               \
    const int q    = lane >> 4;                                               \
    size_t soffA[4];                                                          \
    _Pragma("unroll")                                                         \
    for (int i = 0; i < 4; ++i) {                                             \
        int c = i * 512 + tid;                                                \
        int r = c >> 3;                                                       \
        int j = (c & 7) ^ (r & 7);                                            \
        soffA[i] = (size_t)r * KDIM + j * 8;                                  \
    }                                                                         \
    size_t soffB[3];                                                          \
    _Pragma("unroll")                                                         \
    for (int i = 0; i < 3; ++i) {                                             \
        int c = i * 512 + tid;                                                \
        int r = c >> 3;                                                       \
        int j = (c & 7) ^ (r & 7);                                            \
        soffB[i] = (size_t)r * KDIM + j * 8;                                  \
    }                                                                         \
    f32x4 acc[4][6];                                                          \
    _Pragma("unroll")                                                         \
    for (int i = 0; i < 4; ++i)                                               \
        _Pragma("unroll")                                                     \
        for (int j = 0; j < 6; ++j) acc[i][j] = (f32x4)0.f;

#define R3_STAGE_A(Ad, kk)                                                    \
    _Pragma("unroll")                                                         \
    for (int i = 0; i < 4; ++i)                                               \
        gload_lds16(baseA + soffA[i] + (size_t)(kk) * 64,                     \
                    &Ad[(i * 512 + w * 64) * 8]);

#define R3_STAGE_B(Bd, kk)                                                    \
    _Pragma("unroll")                                                         \
    for (int i = 0; i < 3; ++i)                                               \
        gload_lds16(baseB + soffB[i] + (size_t)(kk) * 64,                     \
                    &Bd[(i * 512 + w * 64) * 8]);

#define R3_FRAG(buf, row, ks)                                                 \
    (*(const f16x8*)&buf[(size_t)(row) * 64 +                                 \
                         ((((ks) * 4 + q) ^ ((row) & 7)) * 8)])

#define R3_COMPUTE(Ab, Bb)                                                    \
    _Pragma("unroll")                                                         \
    for (int ks = 0; ks < 2; ++ks) {                                          \
        f16x8 af[4], bf[6];                                                   \
        _Pragma("unroll")                                                     \
        for (int mt = 0; mt < 4; ++mt)                                        \
            af[mt] = R3_FRAG(Ab, wr + mt * 16 + lm, ks);                      \
        _Pragma("unroll")                                                     \
        for (int nt = 0; nt < 6; ++nt)                                        \
            bf[nt] = R3_FRAG(Bb, wc + nt * 16 + lm, ks);                      \
        __builtin_amdgcn_s_setprio(1);                                        \
        _Pragma("unroll")                                                     \
        for (int mt = 0; mt < 4; ++mt)                                        \
            _Pragma("unroll")                                                 \
            for (int nt = 0; nt < 6; ++nt)                                    \
                acc[mt][nt] = __builtin_amdgcn_mfma_f32_16x16x32_f16(         \
                    af[mt], bf[nt], acc[mt][nt], 0, 0, 0);                    \
        __builtin_amdgcn_s_setprio(0);                                        \
    }

#define R3_TILE(Ab, Bb, SB, Bn, kb, SA, An, ka, WN)                           \
    R3_WAIT(WN);                                                              \
    __builtin_amdgcn_s_barrier();                                             \
    __builtin_amdgcn_sched_barrier(0);                                        \
    if (SB) { R3_STAGE_B(Bn, kb) }                                            \
    if (SA) { R3_STAGE_A(An, ka) }                                            \
    R3_COMPUTE(Ab, Bb)

// KDIM=768 -> 12 tiles, fully peeled. A buf = t%3, B buf = t%2.
// Prologue issue order A(0),B(0),A(1) keeps steady-state vmcnt(4) semantics.
#define R3_KLOOP768()                                                         \
    R3_STAGE_A(As0, 0)                                                        \
    R3_STAGE_B(Bs0, 0)                                                        \
    R3_STAGE_A(As1, 1)                                                        \
    R3_TILE(As0, Bs0, 1, Bs1, 1,  1, As2, 2,  4)                              \
    R3_TILE(As1, Bs1, 1, Bs0, 2,  1, As0, 3,  4)                              \
    R3_TILE(As2, Bs0, 1, Bs1, 3,  1, As1, 4,  4)                              \
    R3_TILE(As0, Bs1, 1, Bs0, 4,  1, As2, 5,  4)                              \
    R3_TILE(As1, Bs0, 1, Bs1, 5,  1, As0, 6,  4)                              \
    R3_TILE(As2, Bs1, 1, Bs0, 6,  1, As1, 7,  4)                              \
    R3_TILE(As0, Bs0, 1, Bs1, 7,  1, As2, 8,  4)                              \
    R3_TILE(As1, Bs1, 1, Bs0, 8,  1, As0, 9,  4)                              \
    R3_TILE(As2, Bs0, 1, Bs1, 9,  1, As1, 10, 4)                              \
    R3_TILE(As0, Bs1, 1, Bs0, 10, 1, As2, 11, 4)                              \
    R3_TILE(As1, Bs0, 1, Bs1, 11, 0, As0, 0,  4)                              \
    R3_TILE(As2, Bs1, 0, Bs0, 0,  0, As0, 0,  0)

// XCD-aware bijective swizzle: nwg = 12*128 = 1536 = 8*192 (divisible).
// Each XCD owns 16 consecutive row-panels x all 12 col-tiles: A panel
// (393 KB) + W (3.5 MB) stay L2-resident per XCD.
#define R3_SWIZZLE()                                                          \
    const int wg   = blockIdx.y * 12 + blockIdx.x;                            \
    const int swz  = (wg & 7) * 192 + (wg >> 3);                              \
    const int row0 = (swz / 12) * 256;                                        \
    const int col0 = (swz % 12) * 192;

// ---------------------------------------------------------------------------
// GEMM2 (col QKV): C = A*W^T + bias -> p f16 [NROW][TD]. grid (12,128) x512.
// ---------------------------------------------------------------------------
__global__ __launch_bounds__(512, 2)
void mfma_gemm_qkv(const f16* __restrict__ A, const f16* __restrict__ W,
                   const float* __restrict__ bias, f16* __restrict__ C)
{
    R3_SWIZZLE()
    R3_PROLOG()
    const f16* baseA = A + (size_t)row0 * KDIM;
    const f16* baseB = W + (size_t)col0 * KDIM;
    R3_KLOOP768()

    // C/D layout: col=lane&15, row=quad*4+reg
    float bv[6];
#pragma unroll
    for (int nt = 0; nt < 6; ++nt) bv[nt] = bias[col0 + wc + nt * 16 + lm];
#pragma unroll
    for (int mt = 0; mt < 4; ++mt) {
        int grow = row0 + wr + mt * 16 + q * 4;
#pragma unroll
        for (int nt = 0; nt < 6; ++nt) {
            int gcol = col0 + wc + nt * 16 + lm;
#pragma unroll
            for (int r = 0; r < 4; ++r)
                C[(size_t)(grow + r) * TD + gcol] = (f16)(acc[mt][nt][r] + bv[nt]);
        }
    }
}

// ---------------------------------------------------------------------------
// GEMM1 (row QKV): same core but scatter epilogue:
//   q -> qt[h][i][s*64+c], k -> kt[h][j][s*64+c], v -> vt[h][s*64+d][j].
// col0 tiles (192-wide) never straddle the 768/1536 q/k/v boundaries.
// ---------------------------------------------------------------------------
__global__ __launch_bounds__(512, 2)
void mfma_gemm_row(const f16* __restrict__ A, const f16* __restrict__ W,
                   const float* __restrict__ bias,
                   f16* __restrict__ qt, f16* __restrict__ kt,
                   f16* __restrict__ vt)
{
    R3_SWIZZLE()
    R3_PROLOG()
    const f16* baseA = A + (size_t)row0 * KDIM;
    const f16* baseB = W + (size_t)col0 * KDIM;
    R3_KLOOP768()

    if (col0 < 1536) {
        f16* dst = (col0 < 768) ? qt : kt;
        const int cbase = (col0 < 768) ? col0 : col0 - 768;
#pragma unroll
        for (int nt = 0; nt < 6; ++nt) {
            int gcol = cbase + wc + nt * 16 + lm;
            int h = gcol >> 6, c = gcol & 63;
            float b = bias[col0 + wc + nt * 16 + lm];
#pragma unroll
            for (int mt = 0; mt < 4; ++mt) {
                int n0 = row0 + wr + mt * 16 + q * 4;
#pragma unroll
                for (int r = 0; r < 4; ++r) {
                    int n = n0 + r;
                    int s = n >> 8, ii = n & 255;
                    dst[(((size_t)h * 256 + ii) * 128 + s) * 64 + c] =
                        (f16)(acc[mt][nt][r] + b);
                }
            }
        }
    } else {
#pragma unroll
        for (int nt = 0; nt < 6; ++nt) {
            int gcol = col0 + wc + nt * 16 + lm;
            int vcol = gcol - 1536;
            int h = vcol >> 6, d = vcol & 63;
            float b = bias[gcol];
#pragma unroll
            for (int mt = 0; mt < 4; ++mt) {
                int n0 = row0 + wr + mt * 16 + q * 4;
                int s = n0 >> 8, j0 = n0 & 255;   // r stays within one s
                f16x4 pack;
#pragma unroll
                for (int r = 0; r < 4; ++r) pack[r] = (f16)(acc[mt][nt][r] + b);
                *(f16x4*)&vt[((((size_t)h * 128 + s) * 64 + d) << 8) + j0] = pack;
            }
        }
    }
}

// ---------------------------------------------------------------------------
// Row logits via MFMA: split-K=4 partials. grid (2, 2, 48): z = h*4+sp.
// ---------------------------------------------------------------------------
__global__ __launch_bounds__(256)
void row_logits_mfma(const f16* __restrict__ qt, const f16* __restrict__ kt,
                     float* __restrict__ lpart)
{
    const int i0 = blockIdx.y * 128;
    const int j0 = blockIdx.x * 128;
    const int h  = blockIdx.z >> 2;
    const int sp = blockIdx.z & 3;
    MFMA_PROLOG(8192)
    const f16* baseA = qt + ((size_t)h * 256 + i0) * 8192 + sp * 2048;
    const f16* baseB = kt + ((size_t)h * 256 + j0) * 8192 + sp * 2048;
    MFMA_KLOOP(baseA, baseB, 2048)

    float* outp = lpart + (size_t)(sp * 12 + h) * 65536;
#pragma unroll
    for (int mt = 0; mt < 4; ++mt) {
        int grow = i0 + wr + mt * 16 + q * 4;
#pragma unroll
        for (int nt = 0; nt < 4; ++nt) {
            int gcol = j0 + wc + nt * 16 + lm;
#pragma unroll
            for (int r = 0; r < 4; ++r)
                outp[(size_t)(grow + r) * 256 + gcol] = acc[mt][nt][r];
        }
    }
}

// ---------------------------------------------------------------------------
// softmax over rows of 256, summing 4 split-K partials; probs out f16.
// ---------------------------------------------------------------------------
__global__ __launch_bounds__(256)
void softmax256_4(const float* __restrict__ lpart, f16* __restrict__ pt)
{
    __shared__ float red[256];
    const int t = threadIdx.x;
    const size_t idx = (size_t)blockIdx.x * 256 + t;
    const size_t P = (size_t)12 * 65536;
    float v = lpart[idx] + lpart[idx + P] + lpart[idx + 2*P] + lpart[idx + 3*P];
    red[t] = v; __syncthreads();
    for (int w = 128; w > 0; w >>= 1) { if (t < w) red[t] = fmaxf(red[t], red[t+w]); __syncthreads(); }
    float m = red[0];
    __syncthreads();
    float e = __expf(v - m);
    red[t] = e; __syncthreads();
    for (int w = 128; w > 0; w >>= 1) { if (t < w) red[t] += red[t+w]; __syncthreads(); }
    pt[idx] = (f16)(e / red[0]);
}

// ---------------------------------------------------------------------------
// Row PV via MFMA: per h, out[i,(s,d)] = sum_j pt[h][i][j] * vt[h][(s,d)][j].
// ---------------------------------------------------------------------------
__global__ __launch_bounds__(256)
void row_pv_mfma(const f16* __restrict__ pt, const f16* __restrict__ vt,
                 float* __restrict__ rout)
{
    const int n0t = blockIdx.x * 128;
    const int i0  = blockIdx.y * 128;
    const int h   = blockIdx.z;
    MFMA_PROLOG(256)
    const f16* baseA = pt + (size_t)h * 65536 + (size_t)i0 * 256;
    const f16* baseB = vt + ((size_t)h * 8192 + n0t) * 256;
    MFMA_KLOOP(baseA, baseB, 256)

#pragma unroll
    for (int mt = 0; mt < 4; ++mt) {
        int irow = i0 + wr + mt * 16 + q * 4;
#pragma unroll
        for (int nt = 0; nt < 4; ++nt) {
            int n = n0t + wc + nt * 16 + lm;
            int s = n >> 6, d = n & 63;
#pragma unroll
            for (int r = 0; r < 4; ++r)
                rout[(size_t)(s * 256 + irow + r) * D_DIM + h * 64 + d] =
                    acc[mt][nt][r];
        }
    }
}

// ---------------------------------------------------------------------------
// out1_h = f16(LN(x + r)); x,r f32. grid NROW, block 256.
// ---------------------------------------------------------------------------
__global__ __launch_bounds__(256)
void add_ln_out16(const float* __restrict__ x, const float* __restrict__ r,
                  const float* __restrict__ g, const float* __restrict__ beta,
                  f16* __restrict__ out16)
{
    __shared__ float red[256];
    const int n = blockIdx.x, t = threadIdx.x;
    const float* xp = x + (size_t)n * D_DIM;
    const float* rp = r + (size_t)n * D_DIM;
    float v[3]; float s = 0.f;
#pragma unroll
    for (int e = 0; e < 3; ++e) { v[e] = xp[t + e*256] + rp[t + e*256]; s += v[e]; }
    red[t] = s; __syncthreads();
    for (int w = 128; w > 0; w >>= 1) { if (t < w) red[t] += red[t+w]; __syncthreads(); }
    float mean = red[0] * (1.f/768.f);
    __syncthreads();
    float sq = 0.f;
#pragma unroll
    for (int e = 0; e < 3; ++e) { float d = v[e] - mean; sq += d*d; }
    red[t] = sq; __syncthreads();
    for (int w = 128; w > 0; w >>= 1) { if (t < w) red[t] += red[t+w]; __syncthreads(); }
    float rstd = rsqrtf(red[0] * (1.f/768.f) + LN_EPS);
#pragma unroll
    for (int e = 0; e < 3; ++e) {
        int idx = t + e*256;
        out16[(size_t)n * D_DIM + idx] = (f16)((v[e] - mean) * rstd * g[idx] + beta[idx]);
    }
}

// ---------------------------------------------------------------------------
// out = LN(x16 + r) f32, in place on r. grid NROW, block 256.
// ---------------------------------------------------------------------------
__global__ __launch_bounds__(256)
void add_ln_in16(const f16* __restrict__ x16, float* __restrict__ r,
                 const float* __restrict__ g, const float* __restrict__ beta)
{
    __shared__ float red[256];
    const int n = blockIdx.x, t = threadIdx.x;
    const f16*   xp = x16 + (size_t)n * D_DIM;
    float*       rp = r   + (size_t)n * D_DIM;
    float v[3]; float s = 0.f;
#pragma unroll
    for (int e = 0; e < 3; ++e) { v[e] = (float)xp[t + e*256] + rp[t + e*256]; s += v[e]; }
    red[t] = s; __syncthreads();
    for (int w = 128; w > 0; w >>= 1) { if (t < w) red[t] += red[t+w]; __syncthreads(); }
    float mean = red[0] * (1.f/768.f);
    __syncthreads();
    float sq = 0.f;
#pragma unroll
    for (int e = 0; e < 3; ++e) { float d = v[e] - mean; sq += d*d; }
    red[t] = sq; __syncthreads();
    for (int w = 128; w > 0; w >>= 1) { if (t < w) red[t] += red[t+w]; __syncthreads(); }
    float rstd = rsqrtf(red[0] * (1.f/768.f) + LN_EPS);
#pragma unroll
    for (int e = 0; e < 3; ++e) {
        int idx = t + e*256;
        rp[idx] = (v[e] - mean) * rstd * g[idx] + beta[idx];
    }
}

// ---------------------------------------------------------------------------
// Column attention via MFMA. One block per (l,h): grid (256, 12), 256 thr.
// ---------------------------------------------------------------------------
__global__ __launch_bounds__(256, 3)
void col_attn_mfma(const f16* __restrict__ p, float* __restrict__ cout)
{
    __shared__ char smem[54272];
    f16* Qs = (f16*)smem;             // [128][72]
    f16* Ks = (f16*)(smem + 18432);   // [128][72]
    f16* Ps = (f16*)smem;             // [128][136] overlay (after barrier)
    f16* Vt = (f16*)(smem + 36864);   // [64][136]

    const int tid  = threadIdx.x;
    const int lane = tid & 63;
    const int w    = tid >> 6;
    const int lm   = lane & 15;
    const int q    = lane >> 4;
    const int l = blockIdx.x, h = blockIdx.y;
    const int ib = w * 32;

    // ---- phase 1: stage Q,K row-major; V transposed into Vt[d][j]
    {
        const int r  = tid >> 1;          // s index 0..127
        const int hc = (tid & 1) * 32;    // c half
        const f16* rowp = p + (size_t)(r * 256 + l) * TD + h * 64 + hc;
#pragma unroll
        for (int cc = 0; cc < 4; ++cc)
            *(float4*)&Qs[r * 72 + hc + cc * 8] = *(const float4*)(rowp + cc * 8);
#pragma unroll
        for (int cc = 0; cc < 4; ++cc)
            *(float4*)&Ks[r * 72 + hc + cc * 8] = *(const float4*)(rowp + 768 + cc * 8);
#pragma unroll
        for (int cc = 0; cc < 4; ++cc) {
            union { float4 f; u16 u[8]; } vb;
            vb.f = *(const float4*)(rowp + 1536 + cc * 8);
#pragma unroll
            for (int e = 0; e < 8; ++e) {
                int d = hc + cc * 8 + e;
                ((u16*)Vt)[d * 136 + r] = vb.u[e];
            }
        }
    }
    __syncthreads();

    // ---- phase 2: S = Q K^T (wave tile 32x128: 2 mt x 8 nt x 2 ksteps)
    f32x4 acc[2][8];
#pragma unroll
    for (int mt = 0; mt < 2; ++mt)
#pragma unroll
        for (int nt = 0; nt < 8; ++nt) acc[mt][nt] = (f32x4)0.f;
#pragma unroll
    for (int ks = 0; ks < 2; ++ks) {
        f16x8 af[2];
#pragma unroll
        for (int mt = 0; mt < 2; ++mt)
            af[mt] = *(const f16x8*)&Qs[(ib + mt * 16 + lm) * 72 + ks * 32 + q * 8];
#pragma unroll
        for (int nt = 0; nt < 8; ++nt) {
            f16x8 bf = *(const f16x8*)&Ks[(nt * 16 + lm) * 72 + ks * 32 + q * 8];
#pragma unroll
            for (int mt = 0; mt < 2; ++mt)
                acc[mt][nt] = __builtin_amdgcn_mfma_f32_16x16x32_f16(
                    af[mt], bf, acc[mt][nt], 0, 0, 0);
        }
    }
    __syncthreads();   // all Qs/Ks frag reads done before Ps overlay writes

    // ---- phase 3: softmax over j in C-layout; write exp to Ps (f16)
    float inv_sum[2][4];
#pragma unroll
    for (int mt = 0; mt < 2; ++mt) {
#pragma unroll
        for (int r = 0; r < 4; ++r) {
            float m = acc[mt][0][r];
#pragma unroll
            for (int nt = 1; nt < 8; ++nt) m = fmaxf(m, acc[mt][nt][r]);
#pragma unroll
            for (int d = 1; d < 16; d <<= 1) m = fmaxf(m, __shfl_xor(m, d));
            float s = 0.f;
#pragma unroll
            for (int nt = 0; nt < 8; ++nt) {
                float e = __expf(acc[mt][nt][r] - m);
                acc[mt][nt][r] = e; s += e;
            }
#pragma unroll
            for (int d = 1; d < 16; d <<= 1) s += __shfl_xor(s, d);
            inv_sum[mt][r] = 1.f / s;
        }
        const int irow = ib + mt * 16 + q * 4;
#pragma unroll
        for (int nt = 0; nt < 8; ++nt) {
            const int jj = nt * 16 + lm;
#pragma unroll
            for (int r = 0; r < 4; ++r)
                Ps[(irow + r) * 136 + jj] = (f16)acc[mt][nt][r];
        }
    }
    __syncthreads();

    // ---- phase 4: O = P~ V (wave tile 32x64: 2 mt x 4 nt x 4 ksteps)
    f32x4 acc2[2][4];
#pragma unroll
    for (int mt = 0; mt < 2; ++mt)
#pragma unroll
        for (int nt = 0; nt < 4; ++nt) acc2[mt][nt] = (f32x4)0.f;
#pragma unroll
    for (int ks = 0; ks < 4; ++ks) {
        f16x8 pf[2];
#pragma unroll
        for (int mt = 0; mt < 2; ++mt)
            pf[mt] = *(const f16x8*)&Ps[(ib + mt * 16 + lm) * 136 + ks * 32 + q * 8];
#pragma unroll
        for (int nt = 0; nt < 4; ++nt) {
            f16x8 vf = *(const f16x8*)&Vt[(nt * 16 + lm) * 136 + ks * 32 + q * 8];
#pragma unroll
            for (int mt = 0; mt < 2; ++mt)
                acc2[mt][nt] = __builtin_amdgcn_mfma_f32_16x16x32_f16(
                    pf[mt], vf, acc2[mt][nt], 0, 0, 0);
        }
    }

    // ---- epilogue: apply deferred 1/sum, write f32
#pragma unroll
    for (int mt = 0; mt < 2; ++mt) {
        const int irow = ib + mt * 16 + q * 4;
#pragma unroll
        for (int nt = 0; nt < 4; ++nt) {
            const int d = nt * 16 + lm;
#pragma unroll
            for (int r = 0; r < 4; ++r)
                cout[(size_t)((irow + r) * 256 + l) * D_DIM + h * 64 + d] =
                    acc2[mt][nt][r] * inv_sum[mt][r];
        }
    }
}

// ---------------------------------------------------------------------------
extern "C" void kernel_launch(void* const* d_in, const int* in_sizes, int n_in,
                              void* d_out, int out_size, void* d_ws, size_t ws_size,
                              hipStream_t stream)
{
    const float* x     = (const float*)d_in[0];
    const float* w_row = (const float*)d_in[1];
    const float* b_row = (const float*)d_in[2];
    const float* w_col = (const float*)d_in[3];
    const float* b_col = (const float*)d_in[4];
    const float* g1    = (const float*)d_in[5];
    const float* be1   = (const float*)d_in[6];
    const float* g2    = (const float*)d_in[7];
    const float* be2   = (const float*)d_in[8];
    float* out = (float*)d_out;

    char* ws = (char*)d_ws;
    f16*   qt     = (f16*)(ws + WS_QT_OFF);
    f16*   kt     = (f16*)(ws + WS_KT_OFF);
    f16*   vt     = (f16*)(ws + WS_VT_OFF);
    f16*   p      = (f16*)(ws + WS_P_OFF);      // col phase, aliases qt/kt/vt
    float* lpart  = (float*)(ws + WS_LPART_OFF);
    f16*   pt     = (f16*)(ws + WS_PT_OFF);
    f16*   xh     = (f16*)(ws + WS_XH_OFF);     // also out1_h after step 5
    f16*   wrh    = (f16*)(ws + WS_WRH_OFF);
    f16*   wch    = (f16*)(ws + WS_WCH_OFF);

    // 0) f32 -> f16 converts
    cvt_f32_f16<<<NROW * D_DIM / 1024, 256, 0, stream>>>(x, xh);
    cvt_f32_f16<<<TD * D_DIM / 1024, 256, 0, stream>>>(w_row, wrh);
    cvt_f32_f16<<<TD * D_DIM / 1024, 256, 0, stream>>>(w_col, wch);
    // 1) row QKV projection (256x192 ring MFMA) -> qt/kt (K-major) + vt (j-major)
    mfma_gemm_row<<<dim3(12, 128), 512, 0, stream>>>(xh, wrh, b_row, qt, kt, vt);
    // 2) tied row logits (MFMA, split-K=4)
    row_logits_mfma<<<dim3(2, 2, 48), 256, 0, stream>>>(qt, kt, lpart);
    // 3) softmax over j (sums 4 partials) -> f16 probs
    softmax256_4<<<H_DIM * L_DIM, 256, 0, stream>>>(lpart, pt);
    // 4) row PV (MFMA) -> d_out (scratch)
    row_pv_mfma<<<dim3(64, 2, H_DIM), 256, 0, stream>>>(pt, vt, out);
    // 5) out1_h = f16(LN(x + row_out))  (xh dead; reuse as out1_h)
    add_ln_out16<<<NROW, 256, 0, stream>>>(x, out, g1, be1, xh);
    // 6) col QKV projection (256x192 ring MFMA) -> p (overwrites qt/kt/vt)
    mfma_gemm_qkv<<<dim3(12, 128), 512, 0, stream>>>(xh, wch, b_col, p);
    // 7) column attention (MFMA) -> d_out (scratch)
    col_attn_mfma<<<dim3(L_DIM, H_DIM), 256, 0, stream>>>(p, out);
    // 8) out = LN(out1_h + col_out), in place on d_out
    add_ln_in16<<<NROW, 256, 0, stream>>>(xh, out, g2, be2);
}